// Round 6
// baseline (190.812 us; speedup 1.0000x reference)
//
#include <hip/hip_runtime.h>
#include <math.h>

#define N 4096
#define NFEAT 512
#define NHID 64
#define NHEADS 8
#define P_PAIRS 65536
#define CAP 128
#define LRELU_ALPHA 0.2f
#define KS1 4   // K-split for layer-1 gemm (K=512 -> 4 x 128)
#define KS2 8   // K-split for layer-2 gemm (K=512 -> 8 x 64)

// ---------------- K1: build CSR from dense adj (one pass over 67 MB) -------
__global__ __launch_bounds__(256) void build_csr(const float* __restrict__ adj,
                                                 int* __restrict__ counts,
                                                 int* __restrict__ cols) {
  int row = blockIdx.x;
  __shared__ int cnt;
  if (threadIdx.x == 0) cnt = 0;
  __syncthreads();
  const float4* arow = (const float4*)(adj + (size_t)row * N);
  for (int c4 = threadIdx.x; c4 < N / 4; c4 += 256) {
    float4 v = arow[c4];
    int base = c4 * 4;
    if (v.x > 0.f) { int k = atomicAdd(&cnt, 1); if (k < CAP) cols[(size_t)row * CAP + k] = base; }
    if (v.y > 0.f) { int k = atomicAdd(&cnt, 1); if (k < CAP) cols[(size_t)row * CAP + k] = base + 1; }
    if (v.z > 0.f) { int k = atomicAdd(&cnt, 1); if (k < CAP) cols[(size_t)row * CAP + k] = base + 2; }
    if (v.w > 0.f) { int k = atomicAdd(&cnt, 1); if (k < CAP) cols[(size_t)row * CAP + k] = base + 3; }
  }
  __syncthreads();
  if (threadIdx.x == 0) counts[row] = cnt < CAP ? cnt : CAP;
}

// ---------------- K2: f32 GEMM, high-intensity split-fragment tiles --------
// Per thread: RM x RN accumulator built from MSUB/NSUB float4 sub-fragments at
// stride TM/MSUB (TN/NSUB), so every LDS read is either a 16-lane broadcast
// (A) or 16 consecutive lanes * 16B (B) -> conflict-free. Intensity:
// 128x128/8x8 = 4.0 FMA per LDS float (the per-CU balance point).
// B_eff col c lives at B[(c>>6)*bHeadStride + k*64 + (c&63)] (covers the
// 8-head interleave and plain [K][64] weights). Output slab blockIdx.z.
template <int TM, int TN, int RM, int RN>
__global__ __launch_bounds__(256) void gemm_big(const float* __restrict__ A, int lda,
                                                const float* __restrict__ B,
                                                size_t bHeadStride,
                                                float* __restrict__ P, size_t slabStride,
                                                int ldc, int kc) {
  constexpr int QA = TM / 64;      // A float4 loads / thread / chunk
  constexpr int QB = TN / 64;      // B float4 loads / thread / chunk
  constexpr int MSUB = RM / 4;
  constexpr int NSUB = RN / 4;
  constexpr int MOFF = TM / MSUB;
  constexpr int NOFF = TN / NSUB;
  constexpr int CPT = TN / RN;     // threads per row group (16)
  __shared__ float As[2][16][TM + 4];  // [k][m] transposed, pad -> 2-way max
  __shared__ float Bs[2][16][TN];      // [k][c]
  const int t = threadIdx.x;
  const int m0 = blockIdx.x * TM;
  const int c0 = blockIdx.y * TN;
  const int kbase = blockIdx.z * kc;
  float* Cp = P + (size_t)blockIdx.z * slabStride;
  float4 ar[QA], br[QB];
  int arow[QA], akq[QA], bkb[QB], bcq[QB];
#pragma unroll
  for (int j = 0; j < QA; ++j) {
    int q = t + j * 256;
    arow[j] = q >> 2;
    akq[j] = (q & 3) * 4;
  }
#pragma unroll
  for (int j = 0; j < QB; ++j) {
    int q = t + j * 256;
    bkb[j] = q / (TN / 4);
    bcq[j] = (q % (TN / 4)) * 4;
  }
  auto loadRegs = [&](int kb0) {
#pragma unroll
    for (int j = 0; j < QA; ++j)
      ar[j] = *(const float4*)(A + (size_t)(m0 + arow[j]) * lda + kb0 + akq[j]);
#pragma unroll
    for (int j = 0; j < QB; ++j) {
      int cg = c0 + bcq[j];
      br[j] = *(const float4*)(B + (size_t)(cg >> 6) * bHeadStride +
                               (size_t)(kb0 + bkb[j]) * 64 + (cg & 63));
    }
  };
  auto storeLds = [&](int buf) {
#pragma unroll
    for (int j = 0; j < QA; ++j) {
      As[buf][akq[j] + 0][arow[j]] = ar[j].x;
      As[buf][akq[j] + 1][arow[j]] = ar[j].y;
      As[buf][akq[j] + 2][arow[j]] = ar[j].z;
      As[buf][akq[j] + 3][arow[j]] = ar[j].w;
    }
#pragma unroll
    for (int j = 0; j < QB; ++j)
      *(float4*)(&Bs[buf][bkb[j]][bcq[j]]) = br[j];
  };
  const int tr = t / CPT, tc = t % CPT;
  float acc[RM][RN] = {};
  const int nch = kc / 16;
  loadRegs(kbase);
  storeLds(0);
  __syncthreads();
  for (int c = 0; c < nch; ++c) {
    int cur = c & 1;
    if (c + 1 < nch) loadRegs(kbase + (c + 1) * 16);  // issue early
#pragma unroll
    for (int k = 0; k < 16; ++k) {
      float av[RM], bv[RN];
#pragma unroll
      for (int s = 0; s < MSUB; ++s) {
        float4 v = *(const float4*)(&As[cur][k][s * MOFF + tr * 4]);
        av[s * 4 + 0] = v.x; av[s * 4 + 1] = v.y;
        av[s * 4 + 2] = v.z; av[s * 4 + 3] = v.w;
      }
#pragma unroll
      for (int s = 0; s < NSUB; ++s) {
        float4 v = *(const float4*)(&Bs[cur][k][s * NOFF + tc * 4]);
        bv[s * 4 + 0] = v.x; bv[s * 4 + 1] = v.y;
        bv[s * 4 + 2] = v.z; bv[s * 4 + 3] = v.w;
      }
#pragma unroll
      for (int i = 0; i < RM; ++i)
#pragma unroll
        for (int j = 0; j < RN; ++j)
          acc[i][j] = fmaf(av[i], bv[j], acc[i][j]);
    }
    if (c + 1 < nch) {
      storeLds(cur ^ 1);  // write-late into the other buffer
      __syncthreads();
    }
  }
#pragma unroll
  for (int si = 0; si < MSUB; ++si)
#pragma unroll
    for (int i = 0; i < 4; ++i) {
      int row = m0 + si * MOFF + tr * 4 + i;
#pragma unroll
      for (int sj = 0; sj < NSUB; ++sj) {
        float4 o = {acc[si * 4 + i][sj * 4 + 0], acc[si * 4 + i][sj * 4 + 1],
                    acc[si * 4 + i][sj * 4 + 2], acc[si * 4 + i][sj * 4 + 3]};
        *(float4*)(Cp + (size_t)row * ldc + c0 + sj * NOFF + tc * 4) = o;
      }
    }
}

// ---------------- K3a: layer-1 fused reduce + e_src/e_dst + col-sum --------
// part: KS1 slabs of [N][512] (heads interleaved). 128 blocks x 32 rows.
__global__ __launch_bounds__(256) void fuse1(const float* __restrict__ part,
                                             const float* __restrict__ a,
                                             float* __restrict__ Wh,
                                             float* __restrict__ esrc,
                                             float* __restrict__ edst,
                                             float* __restrict__ colpart) {
  int t = threadIdx.x;
  int w = t >> 6, lane = t & 63;
  int c0 = w * 128 + lane, c1 = c0 + 64;
  int h0 = 2 * w, h1 = 2 * w + 1;
  float as0 = a[h0 * 128 + lane], ad0 = a[h0 * 128 + 64 + lane];
  float as1 = a[h1 * 128 + lane], ad1 = a[h1 * 128 + 64 + lane];
  float cs0 = 0.f, cs1 = 0.f;
  int i0 = blockIdx.x * 32;
  for (int r = 0; r < 32; ++r) {
    int i = i0 + r;
    size_t base = (size_t)i * 512;
    float v0 = 0.f, v1 = 0.f;
#pragma unroll
    for (int z = 0; z < KS1; ++z) {
      v0 += part[(size_t)z * N * 512 + base + c0];
      v1 += part[(size_t)z * N * 512 + base + c1];
    }
    Wh[base + c0] = v0;
    Wh[base + c1] = v1;
    cs0 += v0;
    cs1 += v1;
    float s0 = v0 * as0, d0 = v0 * ad0;
    float s1 = v1 * as1, d1 = v1 * ad1;
#pragma unroll
    for (int off = 32; off; off >>= 1) {
      s0 += __shfl_xor(s0, off);
      d0 += __shfl_xor(d0, off);
      s1 += __shfl_xor(s1, off);
      d1 += __shfl_xor(d1, off);
    }
    if (lane == 0) {
      esrc[h0 * N + i] = s0;
      edst[h0 * N + i] = d0;
      esrc[h1 * N + i] = s1;
      edst[h1 * N + i] = d1;
    }
  }
  colpart[(size_t)blockIdx.x * 512 + c0] = cs0;
  colpart[(size_t)blockIdx.x * 512 + c1] = cs1;
}

// ---------------- K3b: layer-2 fused reduce + e + col-sum ------------------
__global__ __launch_bounds__(256) void fuse2(const float* __restrict__ part,
                                             const float* __restrict__ a,
                                             float* __restrict__ Wh,
                                             float* __restrict__ esrc,
                                             float* __restrict__ edst,
                                             float* __restrict__ colpart) {
  int t = threadIdx.x;
  int w = t >> 6, lane = t & 63;
  float as = a[lane], ad = a[64 + lane];
  float cs = 0.f;
  int i0 = blockIdx.x * 32 + w * 8;
  for (int r = 0; r < 8; ++r) {
    int i = i0 + r;
    size_t base = (size_t)i * 64;
    float v = 0.f;
#pragma unroll
    for (int z = 0; z < KS2; ++z) v += part[(size_t)z * N * 64 + base + lane];
    Wh[base + lane] = v;
    cs += v;
    float s = v * as, d = v * ad;
#pragma unroll
    for (int off = 32; off; off >>= 1) {
      s += __shfl_xor(s, off);
      d += __shfl_xor(d, off);
    }
    if (lane == 0) {
      esrc[i] = s;
      edst[i] = d;
    }
  }
  colpart[((size_t)blockIdx.x * 4 + w) * 64 + lane] = cs;
}

// ---------------- K4: fold column-sum partials (J slabs of C cols) ---------
__global__ __launch_bounds__(256) void col_sum_final(const float* __restrict__ partial,
                                                     int C, int J,
                                                     float* __restrict__ out) {
  int col = blockIdx.x * 64 + (threadIdx.x & 63);
  int q = threadIdx.x >> 6;
  int per = J / 4;
  float s = 0.f;
  for (int j = q * per; j < (q + 1) * per; ++j) s += partial[(size_t)j * C + col];
  __shared__ float red[4][64];
  red[q][threadIdx.x & 63] = s;
  __syncthreads();
  if (q == 0)
    out[col] = red[0][threadIdx.x] + red[1][threadIdx.x] + red[2][threadIdx.x] +
               red[3][threadIdx.x];
}

// ---------------- K5a: layer-1 attention, one block (8 waves) per node -----
__global__ __launch_bounds__(512) void gat_attn_l1(const float* __restrict__ Wh,
                                                   const float* __restrict__ esrc,
                                                   const float* __restrict__ edst,
                                                   const int* __restrict__ counts,
                                                   const int* __restrict__ cols,
                                                   const float* __restrict__ sumWh,
                                                   float* __restrict__ out) {
  int i = blockIdx.x;
  int tid = threadIdx.x;
  int lane = tid & 63;
  int h = tid >> 6;
  int cnt = counts[i];
  __shared__ int jls[CAP];
  __shared__ float pls[NHEADS][CAP];
  float acc = 0.f;
  if (cnt == 0) {
    acc = sumWh[tid] * (1.0f / N);  // softmax over uniform NEG row
  } else {
    if (tid < cnt) jls[tid] = cols[(size_t)i * CAP + tid];
    __syncthreads();
    float ei = esrc[h * N + i];
    const float* ed = edst + (size_t)h * N;
    float e0 = -1e30f, e1 = -1e30f;
    if (lane < cnt) {
      float e = ei + ed[jls[lane]];
      e0 = (e > 0.f) ? e : LRELU_ALPHA * e;
    }
    if (lane + 64 < cnt) {
      float e = ei + ed[jls[lane + 64]];
      e1 = (e > 0.f) ? e : LRELU_ALPHA * e;
    }
    float m = fmaxf(e0, e1);
#pragma unroll
    for (int off = 32; off; off >>= 1) m = fmaxf(m, __shfl_xor(m, off));
    float p0 = (lane < cnt) ? __expf(e0 - m) : 0.f;
    float p1 = (lane + 64 < cnt) ? __expf(e1 - m) : 0.f;
    float ssum = p0 + p1;
#pragma unroll
    for (int off = 32; off; off >>= 1) ssum += __shfl_xor(ssum, off);
    pls[h][lane] = p0;
    pls[h][lane + 64] = p1;  // own-wave write->read
    int k = 0;
    for (; k + 8 <= cnt; k += 8) {  // 8 gathers in flight
      int j0 = jls[k + 0], j1 = jls[k + 1], j2 = jls[k + 2], j3 = jls[k + 3];
      int j4 = jls[k + 4], j5 = jls[k + 5], j6 = jls[k + 6], j7 = jls[k + 7];
      float4 pa = *(const float4*)(&pls[h][k]);
      float4 pb = *(const float4*)(&pls[h][k + 4]);
      float v0 = Wh[((size_t)j0 << 9) + tid];
      float v1 = Wh[((size_t)j1 << 9) + tid];
      float v2 = Wh[((size_t)j2 << 9) + tid];
      float v3 = Wh[((size_t)j3 << 9) + tid];
      float v4 = Wh[((size_t)j4 << 9) + tid];
      float v5 = Wh[((size_t)j5 << 9) + tid];
      float v6 = Wh[((size_t)j6 << 9) + tid];
      float v7 = Wh[((size_t)j7 << 9) + tid];
      acc = fmaf(pa.x, v0, acc);
      acc = fmaf(pa.y, v1, acc);
      acc = fmaf(pa.z, v2, acc);
      acc = fmaf(pa.w, v3, acc);
      acc = fmaf(pb.x, v4, acc);
      acc = fmaf(pb.y, v5, acc);
      acc = fmaf(pb.z, v6, acc);
      acc = fmaf(pb.w, v7, acc);
    }
    for (; k < cnt; ++k)
      acc = fmaf(pls[h][k], Wh[((size_t)jls[k] << 9) + tid], acc);
    acc /= ssum;
  }
  acc = (acc > 0.f) ? acc : expm1f(acc);  // ELU
  out[((size_t)i << 9) + tid] = acc;
}

// ---------------- K5b: layer-2 attention, one wave per node ----------------
__global__ __launch_bounds__(256) void gat_attn_l2(const float* __restrict__ Wh,
                                                   const float* __restrict__ esrc,
                                                   const float* __restrict__ edst,
                                                   const int* __restrict__ counts,
                                                   const int* __restrict__ cols,
                                                   const float* __restrict__ sumWh,
                                                   float* __restrict__ out) {
  int wv = threadIdx.x >> 6;
  int lane = threadIdx.x & 63;
  int i = (blockIdx.x << 2) + wv;
  int cnt = counts[i];
  __shared__ int jls[4][CAP];
  __shared__ float pls[4][CAP];
  float acc = 0.f;
  if (cnt == 0) {
    acc = sumWh[lane] * (1.0f / N);
  } else {
    const int* cl = cols + (size_t)i * CAP;
    if (lane < cnt) jls[wv][lane] = cl[lane];
    if (lane + 64 < cnt) jls[wv][lane + 64] = cl[lane + 64];
    float ei = esrc[i];
    float e0 = -1e30f, e1 = -1e30f;
    if (lane < cnt) {
      float e = ei + edst[jls[wv][lane]];
      e0 = (e > 0.f) ? e : LRELU_ALPHA * e;
    }
    if (lane + 64 < cnt) {
      float e = ei + edst[jls[wv][lane + 64]];
      e1 = (e > 0.f) ? e : LRELU_ALPHA * e;
    }
    float m = fmaxf(e0, e1);
#pragma unroll
    for (int off = 32; off; off >>= 1) m = fmaxf(m, __shfl_xor(m, off));
    float p0 = (lane < cnt) ? __expf(e0 - m) : 0.f;
    float p1 = (lane + 64 < cnt) ? __expf(e1 - m) : 0.f;
    float ssum = p0 + p1;
#pragma unroll
    for (int off = 32; off; off >>= 1) ssum += __shfl_xor(ssum, off);
    pls[wv][lane] = p0;
    pls[wv][lane + 64] = p1;
    int k = 0;
    for (; k + 4 <= cnt; k += 4) {
      int ja = jls[wv][k + 0], jb = jls[wv][k + 1];
      int jc = jls[wv][k + 2], jd = jls[wv][k + 3];
      float4 pq = *(const float4*)(&pls[wv][k]);
      float va = Wh[((size_t)ja << 6) + lane];
      float vb = Wh[((size_t)jb << 6) + lane];
      float vc = Wh[((size_t)jc << 6) + lane];
      float vd = Wh[((size_t)jd << 6) + lane];
      acc = fmaf(pq.x, va, acc);
      acc = fmaf(pq.y, vb, acc);
      acc = fmaf(pq.z, vc, acc);
      acc = fmaf(pq.w, vd, acc);
    }
    for (; k < cnt; ++k)
      acc = fmaf(pls[wv][k], Wh[((size_t)jls[wv][k] << 6) + lane], acc);
    acc /= ssum;
  }
  acc = (acc > 0.f) ? acc : expm1f(acc);  // ELU
  out[((size_t)i << 6) + lane] = acc;
}

// ---------------- K6a: score GEMM g = hf @ W_score (K=64, wave-per-row) ----
__global__ __launch_bounds__(256) void gemm_row64(const float* __restrict__ A,
                                                  const float* __restrict__ B,
                                                  float* __restrict__ C) {
  __shared__ float Bs[64][64];
  int t = threadIdx.x;
#pragma unroll
  for (int j = 0; j < 4; ++j) {
    int q = t + j * 256;
    int k = q >> 4, cq = (q & 15) * 4;
    *(float4*)(&Bs[k][cq]) = *(const float4*)(B + k * 64 + cq);
  }
  __syncthreads();
  int lane = t & 63, w = t >> 6;
  int r = blockIdx.x * 4 + w;
  float hv = A[(size_t)r * 64 + lane];
  float acc = 0.f;
#pragma unroll
  for (int k = 0; k < 64; ++k) {
    float a = __shfl(hv, k);
    acc = fmaf(a, Bs[k][lane], acc);
  }
  C[(size_t)r * 64 + lane] = acc;
}

// ---------------- K6b: pairwise bilinear scores (4 pairs/wave, float4) -----
__global__ __launch_bounds__(256) void score_quad(const float* __restrict__ g,
                                                  const float* __restrict__ hf,
                                                  const int* __restrict__ p1,
                                                  const int* __restrict__ p2,
                                                  float* __restrict__ out) {
  int w = threadIdx.x >> 6;
  int lane = threadIdx.x & 63;
  int sub = lane >> 4, sl = lane & 15;
  int p = (((blockIdx.x << 2) + w) << 2) + sub;
  int i1 = p1[p], i2 = p2[p];
  float4 ga = *(const float4*)(g + ((size_t)i1 << 6) + sl * 4);
  float4 hb = *(const float4*)(hf + ((size_t)i2 << 6) + sl * 4);
  float v = ga.x * hb.x + ga.y * hb.y + ga.z * hb.z + ga.w * hb.w;
#pragma unroll
  for (int off = 8; off; off >>= 1) v += __shfl_xor(v, off);
  if (sl == 0) out[p] = v;
}

extern "C" void kernel_launch(void* const* d_in, const int* in_sizes, int n_in,
                              void* d_out, int out_size, void* d_ws, size_t ws_size,
                              hipStream_t stream) {
  const float* x       = (const float*)d_in[0];
  const float* adj     = (const float*)d_in[1];
  const float* W_heads = (const float*)d_in[2];
  const float* a_heads = (const float*)d_in[3];
  const float* W_out   = (const float*)d_in[4];
  const float* a_out   = (const float*)d_in[5];
  const float* W_score = (const float*)d_in[6];
  const int* p1        = (const int*)d_in[7];
  const int* p2        = (const int*)d_in[8];
  float* out           = (float*)d_out;

  char* ws = (char*)d_ws;
  size_t off = 0;
  auto alloc = [&](size_t bytes) -> void* {
    void* p = ws + off;
    off += (bytes + 255) & ~(size_t)255;
    return p;
  };
  int*   counts = (int*)alloc((size_t)N * 4);
  int*   cols   = (int*)alloc((size_t)N * CAP * 4);
  float* Wh1    = (float*)alloc((size_t)N * 512 * 4);   // [N][8*64] interleaved
  float* es1    = (float*)alloc((size_t)NHEADS * N * 4);
  float* ed1    = (float*)alloc((size_t)NHEADS * N * 4);
  float* sum1   = (float*)alloc((size_t)512 * 4);
  float* partA  = (float*)alloc((size_t)KS1 * N * 512 * 4);  // 32 MB
  float* cpart1 = (float*)alloc((size_t)128 * 512 * 4);
  float* h1     = (float*)alloc((size_t)N * 512 * 4);
  float* Wh2    = (float*)alloc((size_t)N * 64 * 4);
  float* es2    = (float*)alloc((size_t)N * 4);
  float* ed2    = (float*)alloc((size_t)N * 4);
  float* sum2   = (float*)alloc((size_t)64 * 4);
  float* partB  = (float*)alloc((size_t)KS2 * N * 64 * 4);   // 8 MB
  float* cpart2 = (float*)alloc((size_t)512 * 64 * 4);
  float* hf     = (float*)alloc((size_t)N * 64 * 4);
  float* g      = (float*)alloc((size_t)N * 64 * 4);

  // adjacency -> CSR (shared by both layers)
  build_csr<<<N, 256, 0, stream>>>(adj, counts, cols);

  // ---- layer 1: x[4096x512] @ B_eff[512x512] (heads interleaved) ----
  gemm_big<128, 128, 8, 8><<<dim3(N / 128, 4, KS1), 256, 0, stream>>>(
      x, NFEAT, W_heads, (size_t)NFEAT * 64, partA, (size_t)N * 512, 512,
      NFEAT / KS1);
  fuse1<<<128, 256, 0, stream>>>(partA, a_heads, Wh1, es1, ed1, cpart1);
  col_sum_final<<<8, 256, 0, stream>>>(cpart1, 512, 128, sum1);
  gat_attn_l1<<<N, 512, 0, stream>>>(Wh1, es1, ed1, counts, cols, sum1, h1);

  // ---- layer 2: h1[4096x512] @ W_out[512x64] ----
  gemm_big<128, 64, 8, 4><<<dim3(N / 128, 1, KS2), 256, 0, stream>>>(
      h1, 512, W_out, 0, partB, (size_t)N * 64, 64, 512 / KS2);
  fuse2<<<128, 256, 0, stream>>>(partB, a_out, Wh2, es2, ed2, cpart2);
  col_sum_final<<<1, 256, 0, stream>>>(cpart2, 64, 512, sum2);
  gat_attn_l2<<<N / 4, 256, 0, stream>>>(Wh2, es2, ed2, counts, cols, sum2, hf);

  // ---- pairwise scores ----
  gemm_row64<<<N / 4, 256, 0, stream>>>(hf, W_score, g);
  score_quad<<<P_PAIRS / 16, 256, 0, stream>>>(g, hf, p1, p2, out);
}

// Round 7
// 163.843 us; speedup vs baseline: 1.1646x; 1.1646x over previous
//
#include <hip/hip_runtime.h>
#include <math.h>

#define N 4096
#define NFEAT 512
#define NHID 64
#define NHEADS 8
#define P_PAIRS 65536
#define CAP 128
#define LRELU_ALPHA 0.2f
#define KS2 8   // K-split for layer-2 f32 gemm (K=512 -> 8 x 64)

typedef short bf16x8 __attribute__((ext_vector_type(8)));
typedef float f32x4 __attribute__((ext_vector_type(4)));

__device__ __forceinline__ unsigned short f2bf(float f) {
  unsigned u = __float_as_uint(f);
  u = u + 0x7FFFu + ((u >> 16) & 1u);  // round-to-nearest-even
  return (unsigned short)(u >> 16);
}
__device__ __forceinline__ float bf2f(unsigned short h) {
  return __uint_as_float(((unsigned)h) << 16);
}

// ---------------- K0a: split f32 -> bf16 hi/lo pair -------------------------
__global__ __launch_bounds__(256) void split_hi_lo(const float* __restrict__ src,
                                                   unsigned short* __restrict__ hi,
                                                   unsigned short* __restrict__ lo,
                                                   int n4) {
  int idx = blockIdx.x * 256 + threadIdx.x;
  int stride = gridDim.x * 256;
  for (; idx < n4; idx += stride) {
    float4 v = ((const float4*)src)[idx];
    ushort4 h, l;
    h.x = f2bf(v.x); l.x = f2bf(v.x - bf2f(h.x));
    h.y = f2bf(v.y); l.y = f2bf(v.y - bf2f(h.y));
    h.z = f2bf(v.z); l.z = f2bf(v.z - bf2f(h.z));
    h.w = f2bf(v.w); l.w = f2bf(v.w - bf2f(h.w));
    ((ushort4*)hi)[idx] = h;
    ((ushort4*)lo)[idx] = l;
  }
}

// ---------------- K0b: transpose+split weights: Wt[c][k] = W[c>>6][k][c&63] -
__global__ __launch_bounds__(256) void prep_wt(const float* __restrict__ W,
                                               unsigned short* __restrict__ whi,
                                               unsigned short* __restrict__ wlo) {
  int c = blockIdx.x;
  const float* Wp = W + (size_t)(c >> 6) * 512 * 64 + (c & 63);
  for (int k = threadIdx.x; k < 512; k += 256) {
    float v = Wp[(size_t)k * 64];
    unsigned short hb = f2bf(v);
    whi[(size_t)c * 512 + k] = hb;
    wlo[(size_t)c * 512 + k] = f2bf(v - bf2f(hb));
  }
}

// ---------------- K1: build CSR from dense adj ------------------------------
__global__ __launch_bounds__(256) void build_csr(const float* __restrict__ adj,
                                                 int* __restrict__ counts,
                                                 int* __restrict__ cols) {
  int row = blockIdx.x;
  __shared__ int cnt;
  if (threadIdx.x == 0) cnt = 0;
  __syncthreads();
  const float4* arow = (const float4*)(adj + (size_t)row * N);
  for (int c4 = threadIdx.x; c4 < N / 4; c4 += 256) {
    float4 v = arow[c4];
    int base = c4 * 4;
    if (v.x > 0.f) { int k = atomicAdd(&cnt, 1); if (k < CAP) cols[(size_t)row * CAP + k] = base; }
    if (v.y > 0.f) { int k = atomicAdd(&cnt, 1); if (k < CAP) cols[(size_t)row * CAP + k] = base + 1; }
    if (v.z > 0.f) { int k = atomicAdd(&cnt, 1); if (k < CAP) cols[(size_t)row * CAP + k] = base + 2; }
    if (v.w > 0.f) { int k = atomicAdd(&cnt, 1); if (k < CAP) cols[(size_t)row * CAP + k] = base + 3; }
  }
  __syncthreads();
  if (threadIdx.x == 0) counts[row] = cnt < CAP ? cnt : CAP;
}

// ---------------- K2: layer-1 GEMM via bf16 split-precision MFMA -----------
// C[4096][512] f32 = (Ahi+Alo) @ Beff, dropping lo*lo (rel err ~2^-17).
// Tile 128x64, 8 waves (4x2), wave tile 32x32 = 2x2 frags of 16x16x32.
// A fragment: lane 16g+r holds A[row=r][k=8g+j]; B fragment: lane 16g+c holds
// B[k=8g+j][col=c]. Identical slot->k maps for A and B, so the contraction is
// correct for any HW k-permutation. C/D: col=lane&15, row=4*(lane>>4)+reg
// (HW-verified m89/m91).
__global__ __launch_bounds__(512) void mfma_gemm(const unsigned short* __restrict__ Ahi,
                                                 const unsigned short* __restrict__ Alo,
                                                 const unsigned short* __restrict__ Bhi,
                                                 const unsigned short* __restrict__ Blo,
                                                 float* __restrict__ C) {
  __shared__ unsigned short As[2][128 * 32];  // [hi/lo][m][k32]
  __shared__ unsigned short Bs[2][64 * 32];   // [hi/lo][c][k32]
  const int t = threadIdx.x;
  const int m0 = blockIdx.x * 128;
  const int c0 = blockIdx.y * 64;
  const int lane = t & 63, wave = t >> 6;
  const int g = lane >> 4, r = lane & 15;
  const int wm = (wave >> 1) * 32;  // wave row origin: 0,32,64,96
  const int wn = (wave & 1) * 32;   // wave col origin: 0,32
  // staging: 512 threads, 16B each; A tiles in 1 pass, B hi/lo split by t<256
  const int sar = t >> 2;
  const int sak = (t & 3) * 8;
  const int tb = t & 255;
  const int sbr = tb >> 2;
  const int sbk = (tb & 3) * 8;
  const unsigned short* Bsel = (t < 256) ? Bhi : Blo;
  const int bbuf = (t < 256) ? 0 : 1;
  const f32x4 z = {0.f, 0.f, 0.f, 0.f};
  f32x4 acc[2][2];
  acc[0][0] = z; acc[0][1] = z; acc[1][0] = z; acc[1][1] = z;
  for (int kb = 0; kb < 512; kb += 32) {
    int4 a0 = *(const int4*)(Ahi + (size_t)(m0 + sar) * 512 + kb + sak);
    int4 a1 = *(const int4*)(Alo + (size_t)(m0 + sar) * 512 + kb + sak);
    int4 b0 = *(const int4*)(Bsel + (size_t)(c0 + sbr) * 512 + kb + sbk);
    __syncthreads();  // previous iteration's LDS reads done
    *(int4*)(&As[0][sar * 32 + sak]) = a0;
    *(int4*)(&As[1][sar * 32 + sak]) = a1;
    *(int4*)(&Bs[bbuf][sbr * 32 + sbk]) = b0;
    __syncthreads();
    bf16x8 ah[2], al[2], bh[2], bl[2];
#pragma unroll
    for (int f = 0; f < 2; ++f) {
      ah[f] = *(const bf16x8*)(&As[0][(wm + f * 16 + r) * 32 + 8 * g]);
      al[f] = *(const bf16x8*)(&As[1][(wm + f * 16 + r) * 32 + 8 * g]);
      bh[f] = *(const bf16x8*)(&Bs[0][(wn + f * 16 + r) * 32 + 8 * g]);
      bl[f] = *(const bf16x8*)(&Bs[1][(wn + f * 16 + r) * 32 + 8 * g]);
    }
#pragma unroll
    for (int i = 0; i < 2; ++i)
#pragma unroll
      for (int j = 0; j < 2; ++j) {
        acc[i][j] = __builtin_amdgcn_mfma_f32_16x16x32_bf16(ah[i], bh[j], acc[i][j], 0, 0, 0);
        acc[i][j] = __builtin_amdgcn_mfma_f32_16x16x32_bf16(al[i], bh[j], acc[i][j], 0, 0, 0);
        acc[i][j] = __builtin_amdgcn_mfma_f32_16x16x32_bf16(ah[i], bl[j], acc[i][j], 0, 0, 0);
      }
  }
#pragma unroll
  for (int i = 0; i < 2; ++i)
#pragma unroll
    for (int j = 0; j < 2; ++j)
#pragma unroll
      for (int q = 0; q < 4; ++q) {
        int row = m0 + wm + i * 16 + 4 * g + q;
        int col = c0 + wn + j * 16 + r;
        C[(size_t)row * 512 + col] = acc[i][j][q];
      }
}

// ---------------- K2b: f32 tiled GEMM with K-split (layer 2, verified r4) ---
__global__ __launch_bounds__(256) void gemm_ks(const float* __restrict__ A, int lda,
                                               const float* __restrict__ B, size_t bBlock,
                                               float* __restrict__ P, size_t ksBlock,
                                               int cOff, int ldc, int kc) {
  __shared__ float Asl[16][68];
  __shared__ float Bsl[16][64];
  const float* Bp = B + (size_t)blockIdx.y * bBlock;
  float* Cp = P + (size_t)blockIdx.z * ksBlock + (size_t)blockIdx.y * cOff;
  int m0 = blockIdx.x * 64;
  int t = threadIdx.x;
  int tx = t & 15, ty = t >> 4;
  int lam = t >> 2;
  int lak = (t & 3) * 4;
  int lbk = t >> 4;
  int lbn = (t & 15) * 4;
  int kbase = blockIdx.z * kc;
  float acc[4][4] = {};
  for (int k0 = kbase; k0 < kbase + kc; k0 += 16) {
    float4 av = *(const float4*)(A + (size_t)(m0 + lam) * lda + k0 + lak);
    float4 bv = *(const float4*)(Bp + (size_t)(k0 + lbk) * 64 + lbn);
    Asl[lak + 0][lam] = av.x;
    Asl[lak + 1][lam] = av.y;
    Asl[lak + 2][lam] = av.z;
    Asl[lak + 3][lam] = av.w;
    *(float4*)(&Bsl[lbk][lbn]) = bv;
    __syncthreads();
#pragma unroll
    for (int k = 0; k < 16; ++k) {
      float4 a = *(const float4*)(&Asl[k][ty * 4]);
      float4 b = *(const float4*)(&Bsl[k][tx * 4]);
      float ar[4] = {a.x, a.y, a.z, a.w};
      float br[4] = {b.x, b.y, b.z, b.w};
#pragma unroll
      for (int i = 0; i < 4; i++)
#pragma unroll
        for (int j = 0; j < 4; j++)
          acc[i][j] = fmaf(ar[i], br[j], acc[i][j]);
    }
    __syncthreads();
  }
#pragma unroll
  for (int i = 0; i < 4; i++) {
    float4 o = {acc[i][0], acc[i][1], acc[i][2], acc[i][3]};
    *(float4*)(Cp + (size_t)(m0 + ty * 4 + i) * ldc + tx * 4) = o;
  }
}

// ---------------- K3a: layer-1 e_src/e_dst + col-sum (reads Wh1 directly) --
__global__ __launch_bounds__(256) void ee1(const float* __restrict__ Wh,
                                           const float* __restrict__ a,
                                           float* __restrict__ esrc,
                                           float* __restrict__ edst,
                                           float* __restrict__ colpart) {
  int t = threadIdx.x;
  int w = t >> 6, lane = t & 63;
  int c0 = w * 128 + lane, c1 = c0 + 64;
  int h0 = 2 * w, h1 = 2 * w + 1;
  float as0 = a[h0 * 128 + lane], ad0 = a[h0 * 128 + 64 + lane];
  float as1 = a[h1 * 128 + lane], ad1 = a[h1 * 128 + 64 + lane];
  float cs0 = 0.f, cs1 = 0.f;
  int i0 = blockIdx.x * 32;
  for (int rr = 0; rr < 32; ++rr) {
    int i = i0 + rr;
    size_t base = (size_t)i * 512;
    float v0 = Wh[base + c0];
    float v1 = Wh[base + c1];
    cs0 += v0;
    cs1 += v1;
    float s0 = v0 * as0, d0 = v0 * ad0;
    float s1 = v1 * as1, d1 = v1 * ad1;
#pragma unroll
    for (int off = 32; off; off >>= 1) {
      s0 += __shfl_xor(s0, off);
      d0 += __shfl_xor(d0, off);
      s1 += __shfl_xor(s1, off);
      d1 += __shfl_xor(d1, off);
    }
    if (lane == 0) {
      esrc[h0 * N + i] = s0;
      edst[h0 * N + i] = d0;
      esrc[h1 * N + i] = s1;
      edst[h1 * N + i] = d1;
    }
  }
  colpart[(size_t)blockIdx.x * 512 + c0] = cs0;
  colpart[(size_t)blockIdx.x * 512 + c1] = cs1;
}

// ---------------- K3b: layer-2 fused reduce + e + col-sum ------------------
__global__ __launch_bounds__(256) void fuse2(const float* __restrict__ part,
                                             const float* __restrict__ a,
                                             float* __restrict__ Wh,
                                             float* __restrict__ esrc,
                                             float* __restrict__ edst,
                                             float* __restrict__ colpart) {
  int t = threadIdx.x;
  int w = t >> 6, lane = t & 63;
  float as = a[lane], ad = a[64 + lane];
  float cs = 0.f;
  int i0 = blockIdx.x * 32 + w * 8;
  for (int rr = 0; rr < 8; ++rr) {
    int i = i0 + rr;
    size_t base = (size_t)i * 64;
    float v = 0.f;
#pragma unroll
    for (int z = 0; z < KS2; ++z) v += part[(size_t)z * N * 64 + base + lane];
    Wh[base + lane] = v;
    cs += v;
    float s = v * as, d = v * ad;
#pragma unroll
    for (int off = 32; off; off >>= 1) {
      s += __shfl_xor(s, off);
      d += __shfl_xor(d, off);
    }
    if (lane == 0) {
      esrc[i] = s;
      edst[i] = d;
    }
  }
  colpart[((size_t)blockIdx.x * 4 + w) * 64 + lane] = cs;
}

// ---------------- K4: fold column-sum partials ------------------------------
__global__ __launch_bounds__(256) void col_sum_final(const float* __restrict__ partial,
                                                     int C, int J,
                                                     float* __restrict__ out) {
  int col = blockIdx.x * 64 + (threadIdx.x & 63);
  int q = threadIdx.x >> 6;
  int per = J / 4;
  float s = 0.f;
  for (int j = q * per; j < (q + 1) * per; ++j) s += partial[(size_t)j * C + col];
  __shared__ float red[4][64];
  red[q][threadIdx.x & 63] = s;
  __syncthreads();
  if (q == 0)
    out[col] = red[0][threadIdx.x] + red[1][threadIdx.x] + red[2][threadIdx.x] +
               red[3][threadIdx.x];
}

// ---------------- K5a: layer-1 attention, one block (8 waves) per node -----
__global__ __launch_bounds__(512) void gat_attn_l1(const float* __restrict__ Wh,
                                                   const float* __restrict__ esrc,
                                                   const float* __restrict__ edst,
                                                   const int* __restrict__ counts,
                                                   const int* __restrict__ cols,
                                                   const float* __restrict__ sumWh,
                                                   float* __restrict__ out) {
  int i = blockIdx.x;
  int tid = threadIdx.x;
  int lane = tid & 63;
  int h = tid >> 6;
  int cnt = counts[i];
  __shared__ int jls[CAP];
  __shared__ float pls[NHEADS][CAP];
  float acc = 0.f;
  if (cnt == 0) {
    acc = sumWh[tid] * (1.0f / N);  // softmax over uniform NEG row
  } else {
    if (tid < cnt) jls[tid] = cols[(size_t)i * CAP + tid];
    __syncthreads();
    float ei = esrc[h * N + i];
    const float* ed = edst + (size_t)h * N;
    float e0 = -1e30f, e1 = -1e30f;
    if (lane < cnt) {
      float e = ei + ed[jls[lane]];
      e0 = (e > 0.f) ? e : LRELU_ALPHA * e;
    }
    if (lane + 64 < cnt) {
      float e = ei + ed[jls[lane + 64]];
      e1 = (e > 0.f) ? e : LRELU_ALPHA * e;
    }
    float m = fmaxf(e0, e1);
#pragma unroll
    for (int off = 32; off; off >>= 1) m = fmaxf(m, __shfl_xor(m, off));
    float p0 = (lane < cnt) ? __expf(e0 - m) : 0.f;
    float p1 = (lane + 64 < cnt) ? __expf(e1 - m) : 0.f;
    float ssum = p0 + p1;
#pragma unroll
    for (int off = 32; off; off >>= 1) ssum += __shfl_xor(ssum, off);
    pls[h][lane] = p0;
    pls[h][lane + 64] = p1;  // own-wave write->read
    int k = 0;
    for (; k + 8 <= cnt; k += 8) {  // 8 gathers in flight
      int j0 = jls[k + 0], j1 = jls[k + 1], j2 = jls[k + 2], j3 = jls[k + 3];
      int j4 = jls[k + 4], j5 = jls[k + 5], j6 = jls[k + 6], j7 = jls[k + 7];
      float4 pa = *(const float4*)(&pls[h][k]);
      float4 pb = *(const float4*)(&pls[h][k + 4]);
      float v0 = Wh[((size_t)j0 << 9) + tid];
      float v1 = Wh[((size_t)j1 << 9) + tid];
      float v2 = Wh[((size_t)j2 << 9) + tid];
      float v3 = Wh[((size_t)j3 << 9) + tid];
      float v4 = Wh[((size_t)j4 << 9) + tid];
      float v5 = Wh[((size_t)j5 << 9) + tid];
      float v6 = Wh[((size_t)j6 << 9) + tid];
      float v7 = Wh[((size_t)j7 << 9) + tid];
      acc = fmaf(pa.x, v0, acc);
      acc = fmaf(pa.y, v1, acc);
      acc = fmaf(pa.z, v2, acc);
      acc = fmaf(pa.w, v3, acc);
      acc = fmaf(pb.x, v4, acc);
      acc = fmaf(pb.y, v5, acc);
      acc = fmaf(pb.z, v6, acc);
      acc = fmaf(pb.w, v7, acc);
    }
    for (; k < cnt; ++k)
      acc = fmaf(pls[h][k], Wh[((size_t)jls[k] << 9) + tid], acc);
    acc /= ssum;
  }
  acc = (acc > 0.f) ? acc : expm1f(acc);  // ELU
  out[((size_t)i << 9) + tid] = acc;
}

// ---------------- K5b: layer-2 attention, one wave per node ----------------
__global__ __launch_bounds__(256) void gat_attn_l2(const float* __restrict__ Wh,
                                                   const float* __restrict__ esrc,
                                                   const float* __restrict__ edst,
                                                   const int* __restrict__ counts,
                                                   const int* __restrict__ cols,
                                                   const float* __restrict__ sumWh,
                                                   float* __restrict__ out) {
  int wv = threadIdx.x >> 6;
  int lane = threadIdx.x & 63;
  int i = (blockIdx.x << 2) + wv;
  int cnt = counts[i];
  __shared__ int jls[4][CAP];
  __shared__ float pls[4][CAP];
  float acc = 0.f;
  if (cnt == 0) {
    acc = sumWh[lane] * (1.0f / N);
  } else {
    const int* cl = cols + (size_t)i * CAP;
    if (lane < cnt) jls[wv][lane] = cl[lane];
    if (lane + 64 < cnt) jls[wv][lane + 64] = cl[lane + 64];
    float ei = esrc[i];
    float e0 = -1e30f, e1 = -1e30f;
    if (lane < cnt) {
      float e = ei + edst[jls[wv][lane]];
      e0 = (e > 0.f) ? e : LRELU_ALPHA * e;
    }
    if (lane + 64 < cnt) {
      float e = ei + edst[jls[wv][lane + 64]];
      e1 = (e > 0.f) ? e : LRELU_ALPHA * e;
    }
    float m = fmaxf(e0, e1);
#pragma unroll
    for (int off = 32; off; off >>= 1) m = fmaxf(m, __shfl_xor(m, off));
    float p0 = (lane < cnt) ? __expf(e0 - m) : 0.f;
    float p1 = (lane + 64 < cnt) ? __expf(e1 - m) : 0.f;
    float ssum = p0 + p1;
#pragma unroll
    for (int off = 32; off; off >>= 1) ssum += __shfl_xor(ssum, off);
    pls[wv][lane] = p0;
    pls[wv][lane + 64] = p1;
    int k = 0;
    for (; k + 4 <= cnt; k += 4) {
      int ja = jls[wv][k + 0], jb = jls[wv][k + 1];
      int jc = jls[wv][k + 2], jd = jls[wv][k + 3];
      float4 pq = *(const float4*)(&pls[wv][k]);
      float va = Wh[((size_t)ja << 6) + lane];
      float vb = Wh[((size_t)jb << 6) + lane];
      float vc = Wh[((size_t)jc << 6) + lane];
      float vd = Wh[((size_t)jd << 6) + lane];
      acc = fmaf(pq.x, va, acc);
      acc = fmaf(pq.y, vb, acc);
      acc = fmaf(pq.z, vc, acc);
      acc = fmaf(pq.w, vd, acc);
    }
    for (; k < cnt; ++k)
      acc = fmaf(pls[wv][k], Wh[((size_t)jls[wv][k] << 6) + lane], acc);
    acc /= ssum;
  }
  acc = (acc > 0.f) ? acc : expm1f(acc);  // ELU
  out[((size_t)i << 6) + lane] = acc;
}

// ---------------- K6a: score GEMM g = hf @ W_score (K=64, wave-per-row) ----
__global__ __launch_bounds__(256) void gemm_row64(const float* __restrict__ A,
                                                  const float* __restrict__ B,
                                                  float* __restrict__ C) {
  __shared__ float Bsl[64][64];
  int t = threadIdx.x;
#pragma unroll
  for (int j = 0; j < 4; ++j) {
    int q = t + j * 256;
    int k = q >> 4, cq = (q & 15) * 4;
    *(float4*)(&Bsl[k][cq]) = *(const float4*)(B + k * 64 + cq);
  }
  __syncthreads();
  int lane = t & 63, w = t >> 6;
  int r = blockIdx.x * 4 + w;
  float hv = A[(size_t)r * 64 + lane];
  float acc = 0.f;
#pragma unroll
  for (int k = 0; k < 64; ++k) {
    float a = __shfl(hv, k);
    acc = fmaf(a, Bsl[k][lane], acc);
  }
  C[(size_t)r * 64 + lane] = acc;
}

// ---------------- K6b: pairwise bilinear scores (4 pairs/wave, float4) -----
__global__ __launch_bounds__(256) void score_quad(const float* __restrict__ g,
                                                  const float* __restrict__ hf,
                                                  const int* __restrict__ p1,
                                                  const int* __restrict__ p2,
                                                  float* __restrict__ out) {
  int w = threadIdx.x >> 6;
  int lane = threadIdx.x & 63;
  int sub = lane >> 4, sl = lane & 15;
  int p = (((blockIdx.x << 2) + w) << 2) + sub;
  int i1 = p1[p], i2 = p2[p];
  float4 ga = *(const float4*)(g + ((size_t)i1 << 6) + sl * 4);
  float4 hb = *(const float4*)(hf + ((size_t)i2 << 6) + sl * 4);
  float v = ga.x * hb.x + ga.y * hb.y + ga.z * hb.z + ga.w * hb.w;
#pragma unroll
  for (int off = 8; off; off >>= 1) v += __shfl_xor(v, off);
  if (sl == 0) out[p] = v;
}

extern "C" void kernel_launch(void* const* d_in, const int* in_sizes, int n_in,
                              void* d_out, int out_size, void* d_ws, size_t ws_size,
                              hipStream_t stream) {
  const float* x       = (const float*)d_in[0];
  const float* adj     = (const float*)d_in[1];
  const float* W_heads = (const float*)d_in[2];
  const float* a_heads = (const float*)d_in[3];
  const float* W_out   = (const float*)d_in[4];
  const float* a_out   = (const float*)d_in[5];
  const float* W_score = (const float*)d_in[6];
  const int* p1        = (const int*)d_in[7];
  const int* p2        = (const int*)d_in[8];
  float* out           = (float*)d_out;

  char* ws = (char*)d_ws;
  size_t off = 0;
  auto alloc = [&](size_t bytes) -> void* {
    void* p = ws + off;
    off += (bytes + 255) & ~(size_t)255;
    return p;
  };
  int*   counts = (int*)alloc((size_t)N * 4);
  int*   cols   = (int*)alloc((size_t)N * CAP * 4);
  unsigned short* xhi   = (unsigned short*)alloc((size_t)N * 512 * 2);
  unsigned short* xlo   = (unsigned short*)alloc((size_t)N * 512 * 2);
  unsigned short* wt1hi = (unsigned short*)alloc((size_t)512 * 512 * 2);
  unsigned short* wt1lo = (unsigned short*)alloc((size_t)512 * 512 * 2);
  float* Wh1    = (float*)alloc((size_t)N * 512 * 4);   // [N][8*64] interleaved
  float* es1    = (float*)alloc((size_t)NHEADS * N * 4);
  float* ed1    = (float*)alloc((size_t)NHEADS * N * 4);
  float* sum1   = (float*)alloc((size_t)512 * 4);
  float* cpart1 = (float*)alloc((size_t)128 * 512 * 4);
  float* h1     = (float*)alloc((size_t)N * 512 * 4);
  float* Wh2    = (float*)alloc((size_t)N * 64 * 4);
  float* es2    = (float*)alloc((size_t)N * 4);
  float* ed2    = (float*)alloc((size_t)N * 4);
  float* sum2   = (float*)alloc((size_t)64 * 4);
  float* partB  = (float*)alloc((size_t)KS2 * N * 64 * 4);   // 8 MB
  float* cpart2 = (float*)alloc((size_t)512 * 64 * 4);
  float* hf     = (float*)alloc((size_t)N * 64 * 4);
  float* g      = (float*)alloc((size_t)N * 64 * 4);

  // adjacency -> CSR (shared by both layers)
  build_csr<<<N, 256, 0, stream>>>(adj, counts, cols);

  // ---- bf16 hi/lo prep ----
  split_hi_lo<<<2048, 256, 0, stream>>>(x, xhi, xlo, N * 512 / 4);
  prep_wt<<<512, 256, 0, stream>>>(W_heads, wt1hi, wt1lo);

  // ---- layer 1: MFMA split-precision GEMM -> Wh1 [N][512] f32 ----
  mfma_gemm<<<dim3(N / 128, 8), 512, 0, stream>>>(xhi, xlo, wt1hi, wt1lo, Wh1);
  ee1<<<128, 256, 0, stream>>>(Wh1, a_heads, es1, ed1, cpart1);
  col_sum_final<<<8, 256, 0, stream>>>(cpart1, 512, 128, sum1);
  gat_attn_l1<<<N, 512, 0, stream>>>(Wh1, es1, ed1, counts, cols, sum1, h1);

  // ---- layer 2: f32 K-split GEMM (verified r4 path) ----
  gemm_ks<<<dim3(N / 64, 1, KS2), 256, 0, stream>>>(
      h1, 512, W_out, 0, partB, (size_t)N * 64, 0, 64, 512 / KS2);
  fuse2<<<128, 256, 0, stream>>>(partB, a_out, Wh2, es2, ed2, cpart2);
  col_sum_final<<<1, 256, 0, stream>>>(cpart2, 64, 512, sum2);
  gat_attn_l2<<<N / 4, 256, 0, stream>>>(Wh2, es2, ed2, counts, cols, sum2, hf);

  // ---- pairwise scores ----
  gemm_row64<<<N / 4, 256, 0, stream>>>(hf, W_score, g);
  score_quad<<<P_PAIRS / 16, 256, 0, stream>>>(g, hf, p1, p2, out);
}

// Round 8
// 148.357 us; speedup vs baseline: 1.2862x; 1.1044x over previous
//
#include <hip/hip_runtime.h>
#include <math.h>

#define N 4096
#define NFEAT 512
#define NHID 64
#define NHEADS 8
#define P_PAIRS 65536
#define CAP 128
#define LRELU_ALPHA 0.2f

typedef short bf16x8 __attribute__((ext_vector_type(8)));
typedef float f32x4 __attribute__((ext_vector_type(4)));

__device__ __forceinline__ unsigned short f2bf(float f) {
  unsigned u = __float_as_uint(f);
  u = u + 0x7FFFu + ((u >> 16) & 1u);  // round-to-nearest-even
  return (unsigned short)(u >> 16);
}
__device__ __forceinline__ float bf2f(unsigned short h) {
  return __uint_as_float(((unsigned)h) << 16);
}

// ---------------- K0a: split f32 -> bf16 hi/lo pair -------------------------
__global__ __launch_bounds__(256) void split_hi_lo(const float* __restrict__ src,
                                                   unsigned short* __restrict__ hi,
                                                   unsigned short* __restrict__ lo,
                                                   int n4) {
  int idx = blockIdx.x * 256 + threadIdx.x;
  int stride = gridDim.x * 256;
  for (; idx < n4; idx += stride) {
    float4 v = ((const float4*)src)[idx];
    ushort4 h, l;
    h.x = f2bf(v.x); l.x = f2bf(v.x - bf2f(h.x));
    h.y = f2bf(v.y); l.y = f2bf(v.y - bf2f(h.y));
    h.z = f2bf(v.z); l.z = f2bf(v.z - bf2f(h.z));
    h.w = f2bf(v.w); l.w = f2bf(v.w - bf2f(h.w));
    ((ushort4*)hi)[idx] = h;
    ((ushort4*)lo)[idx] = l;
  }
}

// ---------------- K0b: transpose+split weights: Wt[c][k] = W[c>>6][k][c&63] -
// Works for W_heads ([8][512][64], grid 512) and W_out ([512][64], grid 64).
__global__ __launch_bounds__(256) void prep_wt(const float* __restrict__ W,
                                               unsigned short* __restrict__ whi,
                                               unsigned short* __restrict__ wlo) {
  int c = blockIdx.x;
  const float* Wp = W + (size_t)(c >> 6) * 512 * 64 + (c & 63);
  for (int k = threadIdx.x; k < 512; k += 256) {
    float v = Wp[(size_t)k * 64];
    unsigned short hb = f2bf(v);
    whi[(size_t)c * 512 + k] = hb;
    wlo[(size_t)c * 512 + k] = f2bf(v - bf2f(hb));
  }
}

// ---------------- K1: build CSR from dense adj ------------------------------
__global__ __launch_bounds__(256) void build_csr(const float* __restrict__ adj,
                                                 int* __restrict__ counts,
                                                 int* __restrict__ cols) {
  int row = blockIdx.x;
  __shared__ int cnt;
  if (threadIdx.x == 0) cnt = 0;
  __syncthreads();
  const float4* arow = (const float4*)(adj + (size_t)row * N);
  for (int c4 = threadIdx.x; c4 < N / 4; c4 += 256) {
    float4 v = arow[c4];
    int base = c4 * 4;
    if (v.x > 0.f) { int k = atomicAdd(&cnt, 1); if (k < CAP) cols[(size_t)row * CAP + k] = base; }
    if (v.y > 0.f) { int k = atomicAdd(&cnt, 1); if (k < CAP) cols[(size_t)row * CAP + k] = base + 1; }
    if (v.z > 0.f) { int k = atomicAdd(&cnt, 1); if (k < CAP) cols[(size_t)row * CAP + k] = base + 2; }
    if (v.w > 0.f) { int k = atomicAdd(&cnt, 1); if (k < CAP) cols[(size_t)row * CAP + k] = base + 3; }
  }
  __syncthreads();
  if (threadIdx.x == 0) counts[row] = cnt < CAP ? cnt : CAP;
}

// ---------------- K2: split-precision bf16 MFMA GEMM, double-buffered -------
// C_head_major[by][4096][64] f32 = (Ahi+Alo) @ Beff (drop lo*lo, ~2^-17 rel).
// Tile 128x64, 8 waves (4x2), wave tile 32x32 = 2x2 frags of 16x16x32.
// Same fragment slot->k bijection for A and B (k-permutation invariant);
// C/D: col=lane&15, row=4*(lane>>4)+reg (HW-verified m89/m91). Numerics
// identical to the r7-passing kernel; only staging (dbuf) + C layout changed.
__global__ __launch_bounds__(512) void mfma_gemm(const unsigned short* __restrict__ Ahi,
                                                 const unsigned short* __restrict__ Alo,
                                                 const unsigned short* __restrict__ Bhi,
                                                 const unsigned short* __restrict__ Blo,
                                                 float* __restrict__ C) {
  __shared__ unsigned short As[2][2][128 * 32];  // [buf][hi/lo][m][k32]
  __shared__ unsigned short Bs[2][2][64 * 32];   // [buf][hi/lo][c][k32]
  const int t = threadIdx.x;
  const int m0 = blockIdx.x * 128;
  const int c0 = blockIdx.y * 64;
  const int lane = t & 63, wave = t >> 6;
  const int g = lane >> 4, r = lane & 15;
  const int wm = (wave >> 1) * 32;
  const int wn = (wave & 1) * 32;
  const int sar = t >> 2, sak = (t & 3) * 8;
  const int tb = t & 255;
  const int sbr = tb >> 2, sbk = (tb & 3) * 8;
  const unsigned short* Bsel = (t < 256) ? Bhi : Blo;
  const int bhalf = (t < 256) ? 0 : 1;
  const size_t aOff = (size_t)(m0 + sar) * 512 + sak;
  const size_t bOff = (size_t)(c0 + sbr) * 512 + sbk;
  const f32x4 z = {0.f, 0.f, 0.f, 0.f};
  f32x4 acc[2][2];
  acc[0][0] = z; acc[0][1] = z; acc[1][0] = z; acc[1][1] = z;

  int4 a0 = *(const int4*)(Ahi + aOff);
  int4 a1 = *(const int4*)(Alo + aOff);
  int4 b0 = *(const int4*)(Bsel + bOff);
  *(int4*)(&As[0][0][sar * 32 + sak]) = a0;
  *(int4*)(&As[0][1][sar * 32 + sak]) = a1;
  *(int4*)(&Bs[0][bhalf][sbr * 32 + sbk]) = b0;
  __syncthreads();

  for (int ch = 0; ch < 16; ++ch) {
    const int cur = ch & 1;
    if (ch < 15) {  // issue next-chunk loads early (hide under MFMA)
      int kb = (ch + 1) * 32;
      a0 = *(const int4*)(Ahi + aOff + kb);
      a1 = *(const int4*)(Alo + aOff + kb);
      b0 = *(const int4*)(Bsel + bOff + kb);
    }
    bf16x8 ah[2], al[2], bh[2], bl[2];
#pragma unroll
    for (int f = 0; f < 2; ++f) {
      ah[f] = *(const bf16x8*)(&As[cur][0][(wm + f * 16 + r) * 32 + 8 * g]);
      al[f] = *(const bf16x8*)(&As[cur][1][(wm + f * 16 + r) * 32 + 8 * g]);
      bh[f] = *(const bf16x8*)(&Bs[cur][0][(wn + f * 16 + r) * 32 + 8 * g]);
      bl[f] = *(const bf16x8*)(&Bs[cur][1][(wn + f * 16 + r) * 32 + 8 * g]);
    }
#pragma unroll
    for (int i = 0; i < 2; ++i)
#pragma unroll
      for (int j = 0; j < 2; ++j) {
        acc[i][j] = __builtin_amdgcn_mfma_f32_16x16x32_bf16(ah[i], bh[j], acc[i][j], 0, 0, 0);
        acc[i][j] = __builtin_amdgcn_mfma_f32_16x16x32_bf16(al[i], bh[j], acc[i][j], 0, 0, 0);
        acc[i][j] = __builtin_amdgcn_mfma_f32_16x16x32_bf16(ah[i], bl[j], acc[i][j], 0, 0, 0);
      }
    if (ch < 15) {  // write-late into the other buffer
      *(int4*)(&As[cur ^ 1][0][sar * 32 + sak]) = a0;
      *(int4*)(&As[cur ^ 1][1][sar * 32 + sak]) = a1;
      *(int4*)(&Bs[cur ^ 1][bhalf][sbr * 32 + sbk]) = b0;
      __syncthreads();
    }
  }
  // C head-major: head = blockIdx.y, row stride 64
  float* Cp = C + (size_t)blockIdx.y * N * 64;
#pragma unroll
  for (int i = 0; i < 2; ++i)
#pragma unroll
    for (int j = 0; j < 2; ++j)
#pragma unroll
      for (int q = 0; q < 4; ++q) {
        int row = m0 + wm + i * 16 + 4 * g + q;
        int col = wn + j * 16 + r;
        Cp[(size_t)row * 64 + col] = acc[i][j][q];
      }
}

// ---------------- K3: e_src/e_dst + column-sum from head-major Wh ----------
// grid = heads*32 slices; block: 4 waves x 32 rows (128 rows/slice).
__global__ __launch_bounds__(256) void ee_hm(const float* __restrict__ Wh,
                                             const float* __restrict__ a,
                                             float* __restrict__ esrc,
                                             float* __restrict__ edst,
                                             float* __restrict__ colpart) {
  int h = blockIdx.x >> 5;
  int slice = blockIdx.x & 31;
  int w = threadIdx.x >> 6, lane = threadIdx.x & 63;
  float as = a[h * 128 + lane], ad = a[h * 128 + 64 + lane];
  float cs = 0.f;
  int i0 = slice * 128 + w * 32;
  const float* base = Wh + (size_t)h * N * 64;
  for (int rr = 0; rr < 32; ++rr) {
    int i = i0 + rr;
    float v = base[(size_t)i * 64 + lane];
    cs += v;
    float s = v * as, d = v * ad;
#pragma unroll
    for (int off = 32; off; off >>= 1) {
      s += __shfl_xor(s, off);
      d += __shfl_xor(d, off);
    }
    if (lane == 0) {
      esrc[h * N + i] = s;
      edst[h * N + i] = d;
    }
  }
  __shared__ float red[4][64];
  red[w][lane] = cs;
  __syncthreads();
  if (w == 0)
    colpart[((size_t)h * 32 + slice) * 64 + lane] =
        red[0][lane] + red[1][lane] + red[2][lane] + red[3][lane];
}

// ---------------- K4: fold column-sum partials ------------------------------
__global__ __launch_bounds__(64) void sum_fold(const float* __restrict__ partial,
                                               int J, float* __restrict__ out) {
  int b = blockIdx.x, d = threadIdx.x;
  float s = 0.f;
  for (int j = 0; j < J; ++j) s += partial[((size_t)b * J + j) * 64 + d];
  out[b * 64 + d] = s;
}

// ---------------- K5a: layer-1 attention, wave per (node,head) -------------
// head = blockIdx.x % 8 -> same-head blocks land on one XCD (round-robin),
// so the 1 MB head slab of Wh stays L2-resident. Writes h1 as bf16 hi/lo.
__global__ __launch_bounds__(256) void gat_attn_l1(const float* __restrict__ Wh,
                                                   const float* __restrict__ esrc,
                                                   const float* __restrict__ edst,
                                                   const int* __restrict__ counts,
                                                   const int* __restrict__ cols,
                                                   const float* __restrict__ sumWh,
                                                   unsigned short* __restrict__ hhi,
                                                   unsigned short* __restrict__ hlo) {
  int h = blockIdx.x & 7;
  int wv = threadIdx.x >> 6;
  int lane = threadIdx.x & 63;
  int i = (blockIdx.x >> 3) * 4 + wv;
  int cnt = counts[i];
  __shared__ int jls[4][CAP];
  __shared__ float pls[4][CAP];
  const float* WhH = Wh + (size_t)h * N * 64;
  float acc = 0.f;
  if (cnt == 0) {
    acc = sumWh[h * 64 + lane] * (1.0f / N);  // softmax over uniform NEG row
  } else {
    const int* cl = cols + (size_t)i * CAP;
    if (lane < cnt) jls[wv][lane] = cl[lane];
    if (lane + 64 < cnt) jls[wv][lane + 64] = cl[lane + 64];
    float ei = esrc[h * N + i];
    const float* ed = edst + (size_t)h * N;
    float e0 = -1e30f, e1 = -1e30f;
    if (lane < cnt) {
      float e = ei + ed[jls[wv][lane]];
      e0 = (e > 0.f) ? e : LRELU_ALPHA * e;
    }
    if (lane + 64 < cnt) {
      float e = ei + ed[jls[wv][lane + 64]];
      e1 = (e > 0.f) ? e : LRELU_ALPHA * e;
    }
    float m = fmaxf(e0, e1);
#pragma unroll
    for (int off = 32; off; off >>= 1) m = fmaxf(m, __shfl_xor(m, off));
    float p0 = (lane < cnt) ? __expf(e0 - m) : 0.f;
    float p1 = (lane + 64 < cnt) ? __expf(e1 - m) : 0.f;
    float ssum = p0 + p1;
#pragma unroll
    for (int off = 32; off; off >>= 1) ssum += __shfl_xor(ssum, off);
    pls[wv][lane] = p0;
    pls[wv][lane + 64] = p1;  // own-wave write->read, no barrier needed
    int k = 0;
    for (; k + 8 <= cnt; k += 8) {  // 8 gathers in flight (L2-local rows)
      int j0 = jls[wv][k + 0], j1 = jls[wv][k + 1], j2 = jls[wv][k + 2], j3 = jls[wv][k + 3];
      int j4 = jls[wv][k + 4], j5 = jls[wv][k + 5], j6 = jls[wv][k + 6], j7 = jls[wv][k + 7];
      float4 pa = *(const float4*)(&pls[wv][k]);
      float4 pb = *(const float4*)(&pls[wv][k + 4]);
      float v0 = WhH[((size_t)j0 << 6) + lane];
      float v1 = WhH[((size_t)j1 << 6) + lane];
      float v2 = WhH[((size_t)j2 << 6) + lane];
      float v3 = WhH[((size_t)j3 << 6) + lane];
      float v4 = WhH[((size_t)j4 << 6) + lane];
      float v5 = WhH[((size_t)j5 << 6) + lane];
      float v6 = WhH[((size_t)j6 << 6) + lane];
      float v7 = WhH[((size_t)j7 << 6) + lane];
      acc = fmaf(pa.x, v0, acc);
      acc = fmaf(pa.y, v1, acc);
      acc = fmaf(pa.z, v2, acc);
      acc = fmaf(pa.w, v3, acc);
      acc = fmaf(pb.x, v4, acc);
      acc = fmaf(pb.y, v5, acc);
      acc = fmaf(pb.z, v6, acc);
      acc = fmaf(pb.w, v7, acc);
    }
    for (; k < cnt; ++k)
      acc = fmaf(pls[wv][k], WhH[((size_t)jls[wv][k] << 6) + lane], acc);
    acc /= ssum;
  }
  acc = (acc > 0.f) ? acc : expm1f(acc);  // ELU
  size_t oidx = (size_t)i * 512 + h * 64 + lane;
  unsigned short hb = f2bf(acc);
  hhi[oidx] = hb;
  hlo[oidx] = f2bf(acc - bf2f(hb));
}

// ---------------- K5b: layer-2 attention, one wave per node ----------------
__global__ __launch_bounds__(256) void gat_attn_l2(const float* __restrict__ Wh,
                                                   const float* __restrict__ esrc,
                                                   const float* __restrict__ edst,
                                                   const int* __restrict__ counts,
                                                   const int* __restrict__ cols,
                                                   const float* __restrict__ sumWh,
                                                   float* __restrict__ out) {
  int wv = threadIdx.x >> 6;
  int lane = threadIdx.x & 63;
  int i = (blockIdx.x << 2) + wv;
  int cnt = counts[i];
  __shared__ int jls[4][CAP];
  __shared__ float pls[4][CAP];
  float acc = 0.f;
  if (cnt == 0) {
    acc = sumWh[lane] * (1.0f / N);
  } else {
    const int* cl = cols + (size_t)i * CAP;
    if (lane < cnt) jls[wv][lane] = cl[lane];
    if (lane + 64 < cnt) jls[wv][lane + 64] = cl[lane + 64];
    float ei = esrc[i];
    float e0 = -1e30f, e1 = -1e30f;
    if (lane < cnt) {
      float e = ei + edst[jls[wv][lane]];
      e0 = (e > 0.f) ? e : LRELU_ALPHA * e;
    }
    if (lane + 64 < cnt) {
      float e = ei + edst[jls[wv][lane + 64]];
      e1 = (e > 0.f) ? e : LRELU_ALPHA * e;
    }
    float m = fmaxf(e0, e1);
#pragma unroll
    for (int off = 32; off; off >>= 1) m = fmaxf(m, __shfl_xor(m, off));
    float p0 = (lane < cnt) ? __expf(e0 - m) : 0.f;
    float p1 = (lane + 64 < cnt) ? __expf(e1 - m) : 0.f;
    float ssum = p0 + p1;
#pragma unroll
    for (int off = 32; off; off >>= 1) ssum += __shfl_xor(ssum, off);
    pls[wv][lane] = p0;
    pls[wv][lane + 64] = p1;
    int k = 0;
    for (; k + 4 <= cnt; k += 4) {
      int ja = jls[wv][k + 0], jb = jls[wv][k + 1];
      int jc = jls[wv][k + 2], jd = jls[wv][k + 3];
      float4 pq = *(const float4*)(&pls[wv][k]);
      float va = Wh[((size_t)ja << 6) + lane];
      float vb = Wh[((size_t)jb << 6) + lane];
      float vc = Wh[((size_t)jc << 6) + lane];
      float vd = Wh[((size_t)jd << 6) + lane];
      acc = fmaf(pq.x, va, acc);
      acc = fmaf(pq.y, vb, acc);
      acc = fmaf(pq.z, vc, acc);
      acc = fmaf(pq.w, vd, acc);
    }
    for (; k < cnt; ++k)
      acc = fmaf(pls[wv][k], Wh[((size_t)jls[wv][k] << 6) + lane], acc);
    acc /= ssum;
  }
  acc = (acc > 0.f) ? acc : expm1f(acc);  // ELU
  out[((size_t)i << 6) + lane] = acc;
}

// ---------------- K6a: score GEMM g = hf @ W_score (K=64, wave-per-row) ----
__global__ __launch_bounds__(256) void gemm_row64(const float* __restrict__ A,
                                                  const float* __restrict__ B,
                                                  float* __restrict__ C) {
  __shared__ float Bsl[64][64];
  int t = threadIdx.x;
#pragma unroll
  for (int j = 0; j < 4; ++j) {
    int q = t + j * 256;
    int k = q >> 4, cq = (q & 15) * 4;
    *(float4*)(&Bsl[k][cq]) = *(const float4*)(B + k * 64 + cq);
  }
  __syncthreads();
  int lane = t & 63, w = t >> 6;
  int r = blockIdx.x * 4 + w;
  float hv = A[(size_t)r * 64 + lane];
  float acc = 0.f;
#pragma unroll
  for (int k = 0; k < 64; ++k) {
    float a = __shfl(hv, k);
    acc = fmaf(a, Bsl[k][lane], acc);
  }
  C[(size_t)r * 64 + lane] = acc;
}

// ---------------- K6b: pairwise bilinear scores (4 pairs/wave, float4) -----
__global__ __launch_bounds__(256) void score_quad(const float* __restrict__ g,
                                                  const float* __restrict__ hf,
                                                  const int* __restrict__ p1,
                                                  const int* __restrict__ p2,
                                                  float* __restrict__ out) {
  int w = threadIdx.x >> 6;
  int lane = threadIdx.x & 63;
  int sub = lane >> 4, sl = lane & 15;
  int p = (((blockIdx.x << 2) + w) << 2) + sub;
  int i1 = p1[p], i2 = p2[p];
  float4 ga = *(const float4*)(g + ((size_t)i1 << 6) + sl * 4);
  float4 hb = *(const float4*)(hf + ((size_t)i2 << 6) + sl * 4);
  float v = ga.x * hb.x + ga.y * hb.y + ga.z * hb.z + ga.w * hb.w;
#pragma unroll
  for (int off = 8; off; off >>= 1) v += __shfl_xor(v, off);
  if (sl == 0) out[p] = v;
}

extern "C" void kernel_launch(void* const* d_in, const int* in_sizes, int n_in,
                              void* d_out, int out_size, void* d_ws, size_t ws_size,
                              hipStream_t stream) {
  const float* x       = (const float*)d_in[0];
  const float* adj     = (const float*)d_in[1];
  const float* W_heads = (const float*)d_in[2];
  const float* a_heads = (const float*)d_in[3];
  const float* W_out   = (const float*)d_in[4];
  const float* a_out   = (const float*)d_in[5];
  const float* W_score = (const float*)d_in[6];
  const int* p1        = (const int*)d_in[7];
  const int* p2        = (const int*)d_in[8];
  float* out           = (float*)d_out;

  char* ws = (char*)d_ws;
  size_t off = 0;
  auto alloc = [&](size_t bytes) -> void* {
    void* p = ws + off;
    off += (bytes + 255) & ~(size_t)255;
    return p;
  };
  int*   counts = (int*)alloc((size_t)N * 4);
  int*   cols   = (int*)alloc((size_t)N * CAP * 4);
  unsigned short* xhi   = (unsigned short*)alloc((size_t)N * 512 * 2);
  unsigned short* xlo   = (unsigned short*)alloc((size_t)N * 512 * 2);
  unsigned short* wt1hi = (unsigned short*)alloc((size_t)512 * 512 * 2);
  unsigned short* wt1lo = (unsigned short*)alloc((size_t)512 * 512 * 2);
  unsigned short* wt2hi = (unsigned short*)alloc((size_t)64 * 512 * 2);
  unsigned short* wt2lo = (unsigned short*)alloc((size_t)64 * 512 * 2);
  float* Wh1    = (float*)alloc((size_t)NHEADS * N * 64 * 4);  // head-major [8][N][64]
  float* es1    = (float*)alloc((size_t)NHEADS * N * 4);
  float* ed1    = (float*)alloc((size_t)NHEADS * N * 4);
  float* sum1   = (float*)alloc((size_t)512 * 4);
  float* cpart1 = (float*)alloc((size_t)NHEADS * 32 * 64 * 4);
  unsigned short* h1hi = (unsigned short*)alloc((size_t)N * 512 * 2);
  unsigned short* h1lo = (unsigned short*)alloc((size_t)N * 512 * 2);
  float* Wh2    = (float*)alloc((size_t)N * 64 * 4);
  float* es2    = (float*)alloc((size_t)N * 4);
  float* ed2    = (float*)alloc((size_t)N * 4);
  float* sum2   = (float*)alloc((size_t)64 * 4);
  float* cpart2 = (float*)alloc((size_t)32 * 64 * 4);
  float* hf     = (float*)alloc((size_t)N * 64 * 4);
  float* g      = (float*)alloc((size_t)N * 64 * 4);

  // adjacency -> CSR (shared by both layers)
  build_csr<<<N, 256, 0, stream>>>(adj, counts, cols);

  // ---- bf16 hi/lo prep ----
  split_hi_lo<<<2048, 256, 0, stream>>>(x, xhi, xlo, N * 512 / 4);
  prep_wt<<<512, 256, 0, stream>>>(W_heads, wt1hi, wt1lo);
  prep_wt<<<64, 256, 0, stream>>>(W_out, wt2hi, wt2lo);

  // ---- layer 1: MFMA GEMM -> Wh1 head-major [8][N][64] ----
  mfma_gemm<<<dim3(N / 128, NHEADS), 512, 0, stream>>>(xhi, xlo, wt1hi, wt1lo, Wh1);
  ee_hm<<<NHEADS * 32, 256, 0, stream>>>(Wh1, a_heads, es1, ed1, cpart1);
  sum_fold<<<NHEADS, 64, 0, stream>>>(cpart1, 32, sum1);
  gat_attn_l1<<<(N / 4) * NHEADS, 256, 0, stream>>>(Wh1, es1, ed1, counts, cols,
                                                    sum1, h1hi, h1lo);

  // ---- layer 2: MFMA GEMM (h1 hi/lo) -> Wh2 [N][64] ----
  mfma_gemm<<<dim3(N / 128, 1), 512, 0, stream>>>(h1hi, h1lo, wt2hi, wt2lo, Wh2);
  ee_hm<<<32, 256, 0, stream>>>(Wh2, a_out, es2, ed2, cpart2);
  sum_fold<<<1, 64, 0, stream>>>(cpart2, 32, sum2);
  gat_attn_l2<<<N / 4, 256, 0, stream>>>(Wh2, es2, ed2, counts, cols, sum2, hf);

  // ---- pairwise scores ----
  gemm_row64<<<N / 4, 256, 0, stream>>>(hf, W_score, g);
  score_quad<<<P_PAIRS / 16, 256, 0, stream>>>(g, hf, p1, p2, out);
}

// Round 9
// 129.715 us; speedup vs baseline: 1.4710x; 1.1437x over previous
//
#include <hip/hip_runtime.h>
#include <math.h>

#define N 4096
#define NFEAT 512
#define NHID 64
#define NHEADS 8
#define P_PAIRS 65536
#define CAP 128
#define LRELU_ALPHA 0.2f

typedef short bf16x8 __attribute__((ext_vector_type(8)));
typedef float f32x4 __attribute__((ext_vector_type(4)));

__device__ __forceinline__ unsigned short f2bf(float f) {
  unsigned u = __float_as_uint(f);
  u = u + 0x7FFFu + ((u >> 16) & 1u);  // round-to-nearest-even
  return (unsigned short)(u >> 16);
}
__device__ __forceinline__ float bf2f(unsigned short h) {
  return __uint_as_float(((unsigned)h) << 16);
}

// LDS swizzle for [row][32-short] tiles: bijection within each 8-row stripe,
// spreads 16-lane fragment reads (64B row stride) across all 32 banks.
// s = short offset within row (multiple of 8).
__device__ __forceinline__ int swz(int row, int s) {
  int sl = ((row & 7) * 32 + s) ^ ((row & 7) << 3);
  return (row >> 3) * 256 + sl;
}

// ---------------- K0: transpose+split both weight tensors to bf16 hi/lo ----
// Wt[c][k] = W[c>>6][k][c&63]. blocks 0..511 -> W_heads, 512..575 -> W_out.
__global__ __launch_bounds__(256) void prep_wt(const float* __restrict__ W1,
                                               const float* __restrict__ W2,
                                               unsigned short* __restrict__ w1hi,
                                               unsigned short* __restrict__ w1lo,
                                               unsigned short* __restrict__ w2hi,
                                               unsigned short* __restrict__ w2lo) {
  int b = blockIdx.x;
  const float* W;
  unsigned short *hiP, *loP;
  int c;
  if (b < 512) { W = W1; hiP = w1hi; loP = w1lo; c = b; }
  else         { W = W2; hiP = w2hi; loP = w2lo; c = b - 512; }
  const float* Wp = W + (size_t)(c >> 6) * 512 * 64 + (c & 63);
  for (int k = threadIdx.x; k < 512; k += 256) {
    float v = Wp[(size_t)k * 64];
    unsigned short hb = f2bf(v);
    hiP[(size_t)c * 512 + k] = hb;
    loP[(size_t)c * 512 + k] = f2bf(v - bf2f(hb));
  }
}

// ---------------- K1: build CSR from dense adj ------------------------------
__global__ __launch_bounds__(256) void build_csr(const float* __restrict__ adj,
                                                 int* __restrict__ counts,
                                                 int* __restrict__ cols) {
  int row = blockIdx.x;
  __shared__ int cnt;
  if (threadIdx.x == 0) cnt = 0;
  __syncthreads();
  const float4* arow = (const float4*)(adj + (size_t)row * N);
  for (int c4 = threadIdx.x; c4 < N / 4; c4 += 256) {
    float4 v = arow[c4];
    int base = c4 * 4;
    if (v.x > 0.f) { int k = atomicAdd(&cnt, 1); if (k < CAP) cols[(size_t)row * CAP + k] = base; }
    if (v.y > 0.f) { int k = atomicAdd(&cnt, 1); if (k < CAP) cols[(size_t)row * CAP + k] = base + 1; }
    if (v.z > 0.f) { int k = atomicAdd(&cnt, 1); if (k < CAP) cols[(size_t)row * CAP + k] = base + 2; }
    if (v.w > 0.f) { int k = atomicAdd(&cnt, 1); if (k < CAP) cols[(size_t)row * CAP + k] = base + 3; }
  }
  __syncthreads();
  if (threadIdx.x == 0) counts[row] = cnt < CAP ? cnt : CAP;
}

// ---------------- K2: split-precision bf16 MFMA GEMM, dbuf + LDS swizzle ----
// C_head_major[by][4096][64] f32 = (Ahi+Alo) @ Beff (drop lo*lo, ~2^-17 rel).
// F32A=true: A staged from f32 source, hi/lo split in-register (layer 1).
// F32A=false: A staged from prepped bf16 hi/lo pair (layer 2).
// Tile 128x64, 8 waves (4x2), wave tile 32x32 = 2x2 frags of 16x16x32.
// Fragment slot->k bijection identical for A and B; C/D col=lane&15,
// row=4*(lane>>4)+reg (HW-verified m89/m91). LDS XOR-swizzled (see swz).
template <bool F32A>
__global__ __launch_bounds__(512) void mfma_gemm(const float* __restrict__ Af,
                                                 const unsigned short* __restrict__ Ahi,
                                                 const unsigned short* __restrict__ Alo,
                                                 const unsigned short* __restrict__ Bhi,
                                                 const unsigned short* __restrict__ Blo,
                                                 float* __restrict__ C) {
  __shared__ unsigned short As[2][2][128 * 32];  // [buf][hi/lo][swz(m,k)]
  __shared__ unsigned short Bs[2][2][64 * 32];   // [buf][hi/lo][swz(c,k)]
  const int t = threadIdx.x;
  const int m0 = blockIdx.x * 128;
  const int c0 = blockIdx.y * 64;
  const int lane = t & 63, wave = t >> 6;
  const int g = lane >> 4, r = lane & 15;
  const int wm = (wave >> 1) * 32;
  const int wn = (wave & 1) * 32;
  const int sar = t >> 2, sak = (t & 3) * 8;
  const int tb = t & 255;
  const int sbr = tb >> 2, sbk = (tb & 3) * 8;
  const unsigned short* Bsel = (t < 256) ? Bhi : Blo;
  const int bhalf = (t < 256) ? 0 : 1;
  const int idxA = swz(sar, sak);
  const int idxB = swz(sbr, sbk);
  const size_t aOff = (size_t)(m0 + sar) * 512 + sak;
  const size_t bOff = (size_t)(c0 + sbr) * 512 + sbk;
  const f32x4 z = {0.f, 0.f, 0.f, 0.f};
  f32x4 acc[2][2];
  acc[0][0] = z; acc[0][1] = z; acc[1][0] = z; acc[1][1] = z;

  int4 a0, a1, b0;
  auto loadRegs = [&](int kb) {
    if constexpr (F32A) {
      float4 v0 = *(const float4*)(Af + aOff + kb);
      float4 v1 = *(const float4*)(Af + aOff + kb + 4);
      unsigned h0 = f2bf(v0.x), h1 = f2bf(v0.y), h2 = f2bf(v0.z), h3 = f2bf(v0.w);
      unsigned h4 = f2bf(v1.x), h5 = f2bf(v1.y), h6 = f2bf(v1.z), h7 = f2bf(v1.w);
      unsigned l0 = f2bf(v0.x - bf2f(h0)), l1 = f2bf(v0.y - bf2f(h1));
      unsigned l2 = f2bf(v0.z - bf2f(h2)), l3 = f2bf(v0.w - bf2f(h3));
      unsigned l4 = f2bf(v1.x - bf2f(h4)), l5 = f2bf(v1.y - bf2f(h5));
      unsigned l6 = f2bf(v1.z - bf2f(h6)), l7 = f2bf(v1.w - bf2f(h7));
      a0.x = h0 | (h1 << 16); a0.y = h2 | (h3 << 16);
      a0.z = h4 | (h5 << 16); a0.w = h6 | (h7 << 16);
      a1.x = l0 | (l1 << 16); a1.y = l2 | (l3 << 16);
      a1.z = l4 | (l5 << 16); a1.w = l6 | (l7 << 16);
    } else {
      a0 = *(const int4*)(Ahi + aOff + kb);
      a1 = *(const int4*)(Alo + aOff + kb);
    }
    b0 = *(const int4*)(Bsel + bOff + kb);
  };
  auto storeLds = [&](int buf) {
    *(int4*)(&As[buf][0][idxA]) = a0;
    *(int4*)(&As[buf][1][idxA]) = a1;
    *(int4*)(&Bs[buf][bhalf][idxB]) = b0;
  };

  loadRegs(0);
  storeLds(0);
  __syncthreads();

  for (int ch = 0; ch < 16; ++ch) {
    const int cur = ch & 1;
    if (ch < 15) loadRegs((ch + 1) * 32);  // issue early, hide under MFMA
    bf16x8 ah[2], al[2], bh[2], bl[2];
#pragma unroll
    for (int f = 0; f < 2; ++f) {
      int ia = swz(wm + f * 16 + r, 8 * g);
      int ib = swz(wn + f * 16 + r, 8 * g);
      ah[f] = *(const bf16x8*)(&As[cur][0][ia]);
      al[f] = *(const bf16x8*)(&As[cur][1][ia]);
      bh[f] = *(const bf16x8*)(&Bs[cur][0][ib]);
      bl[f] = *(const bf16x8*)(&Bs[cur][1][ib]);
    }
#pragma unroll
    for (int i = 0; i < 2; ++i)
#pragma unroll
      for (int j = 0; j < 2; ++j) {
        acc[i][j] = __builtin_amdgcn_mfma_f32_16x16x32_bf16(ah[i], bh[j], acc[i][j], 0, 0, 0);
        acc[i][j] = __builtin_amdgcn_mfma_f32_16x16x32_bf16(al[i], bh[j], acc[i][j], 0, 0, 0);
        acc[i][j] = __builtin_amdgcn_mfma_f32_16x16x32_bf16(ah[i], bl[j], acc[i][j], 0, 0, 0);
      }
    if (ch < 15) {
      storeLds(cur ^ 1);  // write-late into the other buffer
      __syncthreads();
    }
  }
  float* Cp = C + (size_t)blockIdx.y * N * 64;  // head-major
#pragma unroll
  for (int i = 0; i < 2; ++i)
#pragma unroll
    for (int j = 0; j < 2; ++j)
#pragma unroll
      for (int q = 0; q < 4; ++q) {
        int row = m0 + wm + i * 16 + 4 * g + q;
        int col = wn + j * 16 + r;
        Cp[(size_t)row * 64 + col] = acc[i][j][q];
      }
}

// ---------------- K3: e_src/e_dst + atomic column-sum (head-major Wh) ------
// grid = heads*32 slices; block: 4 waves x 32 rows. sumAtomic must be zeroed.
__global__ __launch_bounds__(256) void ee_hm(const float* __restrict__ Wh,
                                             const float* __restrict__ a,
                                             float* __restrict__ esrc,
                                             float* __restrict__ edst,
                                             float* __restrict__ sumAtomic) {
  int h = blockIdx.x >> 5;
  int slice = blockIdx.x & 31;
  int w = threadIdx.x >> 6, lane = threadIdx.x & 63;
  float as = a[h * 128 + lane], ad = a[h * 128 + 64 + lane];
  float cs = 0.f;
  int i0 = slice * 128 + w * 32;
  const float* base = Wh + (size_t)h * N * 64;
  for (int rr = 0; rr < 32; ++rr) {
    int i = i0 + rr;
    float v = base[(size_t)i * 64 + lane];
    cs += v;
    float s = v * as, d = v * ad;
#pragma unroll
    for (int off = 32; off; off >>= 1) {
      s += __shfl_xor(s, off);
      d += __shfl_xor(d, off);
    }
    if (lane == 0) {
      esrc[h * N + i] = s;
      edst[h * N + i] = d;
    }
  }
  __shared__ float red[4][64];
  red[w][lane] = cs;
  __syncthreads();
  if (w == 0)
    atomicAdd(&sumAtomic[h * 64 + lane],
              red[0][lane] + red[1][lane] + red[2][lane] + red[3][lane]);
}

// ---------------- K5a: layer-1 attention, wave per (node,head) -------------
// head = blockIdx % 8 -> same-head blocks share an XCD (round-robin), keeping
// the 1 MB head slab L2-resident. Writes h1 as bf16 hi/lo for the next GEMM.
__global__ __launch_bounds__(256) void gat_attn_l1(const float* __restrict__ Wh,
                                                   const float* __restrict__ esrc,
                                                   const float* __restrict__ edst,
                                                   const int* __restrict__ counts,
                                                   const int* __restrict__ cols,
                                                   const float* __restrict__ sumWh,
                                                   unsigned short* __restrict__ hhi,
                                                   unsigned short* __restrict__ hlo) {
  int h = blockIdx.x & 7;
  int wv = threadIdx.x >> 6;
  int lane = threadIdx.x & 63;
  int i = (blockIdx.x >> 3) * 4 + wv;
  int cnt = counts[i];
  __shared__ int jls[4][CAP];
  __shared__ float pls[4][CAP];
  const float* WhH = Wh + (size_t)h * N * 64;
  float acc = 0.f;
  if (cnt == 0) {
    acc = sumWh[h * 64 + lane] * (1.0f / N);  // softmax over uniform NEG row
  } else {
    const int* cl = cols + (size_t)i * CAP;
    if (lane < cnt) jls[wv][lane] = cl[lane];
    if (lane + 64 < cnt) jls[wv][lane + 64] = cl[lane + 64];
    float ei = esrc[h * N + i];
    const float* ed = edst + (size_t)h * N;
    float e0 = -1e30f, e1 = -1e30f;
    if (lane < cnt) {
      float e = ei + ed[jls[wv][lane]];
      e0 = (e > 0.f) ? e : LRELU_ALPHA * e;
    }
    if (lane + 64 < cnt) {
      float e = ei + ed[jls[wv][lane + 64]];
      e1 = (e > 0.f) ? e : LRELU_ALPHA * e;
    }
    float m = fmaxf(e0, e1);
#pragma unroll
    for (int off = 32; off; off >>= 1) m = fmaxf(m, __shfl_xor(m, off));
    float p0 = (lane < cnt) ? __expf(e0 - m) : 0.f;
    float p1 = (lane + 64 < cnt) ? __expf(e1 - m) : 0.f;
    float ssum = p0 + p1;
#pragma unroll
    for (int off = 32; off; off >>= 1) ssum += __shfl_xor(ssum, off);
    pls[wv][lane] = p0;
    pls[wv][lane + 64] = p1;  // own-wave write->read, no barrier needed
    int k = 0;
    for (; k + 8 <= cnt; k += 8) {  // 8 gathers in flight (L2-local rows)
      int j0 = jls[wv][k + 0], j1 = jls[wv][k + 1], j2 = jls[wv][k + 2], j3 = jls[wv][k + 3];
      int j4 = jls[wv][k + 4], j5 = jls[wv][k + 5], j6 = jls[wv][k + 6], j7 = jls[wv][k + 7];
      float4 pa = *(const float4*)(&pls[wv][k]);
      float4 pb = *(const float4*)(&pls[wv][k + 4]);
      float v0 = WhH[((size_t)j0 << 6) + lane];
      float v1 = WhH[((size_t)j1 << 6) + lane];
      float v2 = WhH[((size_t)j2 << 6) + lane];
      float v3 = WhH[((size_t)j3 << 6) + lane];
      float v4 = WhH[((size_t)j4 << 6) + lane];
      float v5 = WhH[((size_t)j5 << 6) + lane];
      float v6 = WhH[((size_t)j6 << 6) + lane];
      float v7 = WhH[((size_t)j7 << 6) + lane];
      acc = fmaf(pa.x, v0, acc);
      acc = fmaf(pa.y, v1, acc);
      acc = fmaf(pa.z, v2, acc);
      acc = fmaf(pa.w, v3, acc);
      acc = fmaf(pb.x, v4, acc);
      acc = fmaf(pb.y, v5, acc);
      acc = fmaf(pb.z, v6, acc);
      acc = fmaf(pb.w, v7, acc);
    }
    for (; k < cnt; ++k)
      acc = fmaf(pls[wv][k], WhH[((size_t)jls[wv][k] << 6) + lane], acc);
    acc /= ssum;
  }
  acc = (acc > 0.f) ? acc : expm1f(acc);  // ELU
  size_t oidx = (size_t)i * 512 + h * 64 + lane;
  unsigned short hb = f2bf(acc);
  hhi[oidx] = hb;
  hlo[oidx] = f2bf(acc - bf2f(hb));
}

// ---------------- K5b: layer-2 attention + fused g = hf @ W_score ----------
__global__ __launch_bounds__(256) void gat_attn_l2(const float* __restrict__ Wh,
                                                   const float* __restrict__ esrc,
                                                   const float* __restrict__ edst,
                                                   const int* __restrict__ counts,
                                                   const int* __restrict__ cols,
                                                   const float* __restrict__ sumWh,
                                                   const float* __restrict__ Wsc,
                                                   float* __restrict__ hf,
                                                   float* __restrict__ g) {
  __shared__ float Ws[64][64];
  int t = threadIdx.x;
#pragma unroll
  for (int j = 0; j < 4; ++j) {
    int q = t + j * 256;
    int k = q >> 4, cq = (q & 15) * 4;
    *(float4*)(&Ws[k][cq]) = *(const float4*)(Wsc + k * 64 + cq);
  }
  __syncthreads();
  int wv = t >> 6;
  int lane = t & 63;
  int i = (blockIdx.x << 2) + wv;
  int cnt = counts[i];
  __shared__ int jls[4][CAP];
  __shared__ float pls[4][CAP];
  float acc = 0.f;
  if (cnt == 0) {
    acc = sumWh[lane] * (1.0f / N);
  } else {
    const int* cl = cols + (size_t)i * CAP;
    if (lane < cnt) jls[wv][lane] = cl[lane];
    if (lane + 64 < cnt) jls[wv][lane + 64] = cl[lane + 64];
    float ei = esrc[i];
    float e0 = -1e30f, e1 = -1e30f;
    if (lane < cnt) {
      float e = ei + edst[jls[wv][lane]];
      e0 = (e > 0.f) ? e : LRELU_ALPHA * e;
    }
    if (lane + 64 < cnt) {
      float e = ei + edst[jls[wv][lane + 64]];
      e1 = (e > 0.f) ? e : LRELU_ALPHA * e;
    }
    float m = fmaxf(e0, e1);
#pragma unroll
    for (int off = 32; off; off >>= 1) m = fmaxf(m, __shfl_xor(m, off));
    float p0 = (lane < cnt) ? __expf(e0 - m) : 0.f;
    float p1 = (lane + 64 < cnt) ? __expf(e1 - m) : 0.f;
    float ssum = p0 + p1;
#pragma unroll
    for (int off = 32; off; off >>= 1) ssum += __shfl_xor(ssum, off);
    pls[wv][lane] = p0;
    pls[wv][lane + 64] = p1;
    int k = 0;
    for (; k + 4 <= cnt; k += 4) {
      int ja = jls[wv][k + 0], jb = jls[wv][k + 1];
      int jc = jls[wv][k + 2], jd = jls[wv][k + 3];
      float4 pq = *(const float4*)(&pls[wv][k]);
      float va = Wh[((size_t)ja << 6) + lane];
      float vb = Wh[((size_t)jb << 6) + lane];
      float vc = Wh[((size_t)jc << 6) + lane];
      float vd = Wh[((size_t)jd << 6) + lane];
      acc = fmaf(pq.x, va, acc);
      acc = fmaf(pq.y, vb, acc);
      acc = fmaf(pq.z, vc, acc);
      acc = fmaf(pq.w, vd, acc);
    }
    for (; k < cnt; ++k)
      acc = fmaf(pls[wv][k], Wh[((size_t)jls[wv][k] << 6) + lane], acc);
    acc /= ssum;
  }
  acc = (acc > 0.f) ? acc : expm1f(acc);  // ELU
  hf[((size_t)i << 6) + lane] = acc;
  float gacc = 0.f;
#pragma unroll
  for (int k = 0; k < 64; ++k)
    gacc = fmaf(__shfl(acc, k), Ws[k][lane], gacc);
  g[((size_t)i << 6) + lane] = gacc;
}

// ---------------- K6: pairwise bilinear scores (4 pairs/wave, float4) ------
__global__ __launch_bounds__(256) void score_quad(const float* __restrict__ g,
                                                  const float* __restrict__ hf,
                                                  const int* __restrict__ p1,
                                                  const int* __restrict__ p2,
                                                  float* __restrict__ out) {
  int w = threadIdx.x >> 6;
  int lane = threadIdx.x & 63;
  int sub = lane >> 4, sl = lane & 15;
  int p = (((blockIdx.x << 2) + w) << 2) + sub;
  int i1 = p1[p], i2 = p2[p];
  float4 ga = *(const float4*)(g + ((size_t)i1 << 6) + sl * 4);
  float4 hb = *(const float4*)(hf + ((size_t)i2 << 6) + sl * 4);
  float v = ga.x * hb.x + ga.y * hb.y + ga.z * hb.z + ga.w * hb.w;
#pragma unroll
  for (int off = 8; off; off >>= 1) v += __shfl_xor(v, off);
  if (sl == 0) out[p] = v;
}

extern "C" void kernel_launch(void* const* d_in, const int* in_sizes, int n_in,
                              void* d_out, int out_size, void* d_ws, size_t ws_size,
                              hipStream_t stream) {
  const float* x       = (const float*)d_in[0];
  const float* adj     = (const float*)d_in[1];
  const float* W_heads = (const float*)d_in[2];
  const float* a_heads = (const float*)d_in[3];
  const float* W_out   = (const float*)d_in[4];
  const float* a_out   = (const float*)d_in[5];
  const float* W_score = (const float*)d_in[6];
  const int* p1        = (const int*)d_in[7];
  const int* p2        = (const int*)d_in[8];
  float* out           = (float*)d_out;

  char* ws = (char*)d_ws;
  size_t off = 0;
  auto alloc = [&](size_t bytes) -> void* {
    void* p = ws + off;
    off += (bytes + 255) & ~(size_t)255;
    return p;
  };
  int*   counts = (int*)alloc((size_t)N * 4);
  int*   cols   = (int*)alloc((size_t)N * CAP * 4);
  unsigned short* wt1hi = (unsigned short*)alloc((size_t)512 * 512 * 2);
  unsigned short* wt1lo = (unsigned short*)alloc((size_t)512 * 512 * 2);
  unsigned short* wt2hi = (unsigned short*)alloc((size_t)64 * 512 * 2);
  unsigned short* wt2lo = (unsigned short*)alloc((size_t)64 * 512 * 2);
  float* Wh1    = (float*)alloc((size_t)NHEADS * N * 64 * 4);  // head-major [8][N][64]
  float* es1    = (float*)alloc((size_t)NHEADS * N * 4);
  float* ed1    = (float*)alloc((size_t)NHEADS * N * 4);
  float* sum1   = (float*)alloc((size_t)512 * 4);
  unsigned short* h1hi = (unsigned short*)alloc((size_t)N * 512 * 2);
  unsigned short* h1lo = (unsigned short*)alloc((size_t)N * 512 * 2);
  float* Wh2    = (float*)alloc((size_t)N * 64 * 4);
  float* es2    = (float*)alloc((size_t)N * 4);
  float* ed2    = (float*)alloc((size_t)N * 4);
  float* sum2   = (float*)alloc((size_t)64 * 4);
  float* hf     = (float*)alloc((size_t)N * 64 * 4);
  float* g      = (float*)alloc((size_t)N * 64 * 4);

  // zero the atomic column-sum accumulators (graph-capture-safe)
  hipMemsetAsync(sum1, 0, 512 * 4, stream);
  hipMemsetAsync(sum2, 0, 64 * 4, stream);

  // adjacency -> CSR (shared by both layers)
  build_csr<<<N, 256, 0, stream>>>(adj, counts, cols);

  // weights -> transposed bf16 hi/lo
  prep_wt<<<576, 256, 0, stream>>>(W_heads, W_out, wt1hi, wt1lo, wt2hi, wt2lo);

  // ---- layer 1: MFMA GEMM (f32 A converted in-kernel) -> Wh1 [8][N][64] ----
  mfma_gemm<true><<<dim3(N / 128, NHEADS), 512, 0, stream>>>(
      x, nullptr, nullptr, wt1hi, wt1lo, Wh1);
  ee_hm<<<NHEADS * 32, 256, 0, stream>>>(Wh1, a_heads, es1, ed1, sum1);
  gat_attn_l1<<<(N / 4) * NHEADS, 256, 0, stream>>>(Wh1, es1, ed1, counts, cols,
                                                    sum1, h1hi, h1lo);

  // ---- layer 2: MFMA GEMM (h1 hi/lo) -> Wh2 [N][64] ----
  mfma_gemm<false><<<dim3(N / 128, 1), 512, 0, stream>>>(
      nullptr, h1hi, h1lo, wt2hi, wt2lo, Wh2);
  ee_hm<<<32, 256, 0, stream>>>(Wh2, a_out, es2, ed2, sum2);
  gat_attn_l2<<<N / 4, 256, 0, stream>>>(Wh2, es2, ed2, counts, cols, sum2,
                                         W_score, hf, g);

  // ---- pairwise scores ----
  score_quad<<<P_PAIRS / 16, 256, 0, stream>>>(g, hf, p1, p2, out);
}

// Round 10
// 101.983 us; speedup vs baseline: 1.8710x; 1.2719x over previous
//
#include <hip/hip_runtime.h>
#include <math.h>

#define N 4096
#define NFEAT 512
#define NHID 64
#define NHEADS 8
#define P_PAIRS 65536
#define CAP 128
#define LRELU_ALPHA 0.2f

typedef short bf16x8 __attribute__((ext_vector_type(8)));
typedef float f32x4 __attribute__((ext_vector_type(4)));

__device__ __forceinline__ unsigned short f2bf(float f) {
  unsigned u = __float_as_uint(f);
  u = u + 0x7FFFu + ((u >> 16) & 1u);  // round-to-nearest-even
  return (unsigned short)(u >> 16);
}
__device__ __forceinline__ float bf2f(unsigned short h) {
  return __uint_as_float(((unsigned)h) << 16);
}

// LDS swizzle for [row][32-short] tiles: bijection within each 8-row stripe,
// spreads 16-lane fragment reads (64B row stride) across all 32 banks.
__device__ __forceinline__ int swz(int row, int s) {
  int sl = ((row & 7) * 32 + s) ^ ((row & 7) << 3);
  return (row >> 3) * 256 + sl;
}

// ---------------- K1: fused prep — CSR + weight transpose/split + zeroing --
// blocks [0,4096): CSR row; block 0 also zeros the atomic sum accumulators.
// blocks [4096,4672): weight column c-4096 -> transposed bf16 hi/lo.
__global__ __launch_bounds__(256) void prep_all(const float* __restrict__ adj,
                                                const float* __restrict__ W1,
                                                const float* __restrict__ W2,
                                                int* __restrict__ counts,
                                                int* __restrict__ cols,
                                                unsigned short* __restrict__ w1hi,
                                                unsigned short* __restrict__ w1lo,
                                                unsigned short* __restrict__ w2hi,
                                                unsigned short* __restrict__ w2lo,
                                                float* __restrict__ sum1,
                                                float* __restrict__ sum2) {
  int b = blockIdx.x;
  if (b < N) {
    if (b == 0) {
      for (int t = threadIdx.x; t < 512; t += 256) sum1[t] = 0.f;
      if (threadIdx.x < 64) sum2[threadIdx.x] = 0.f;
    }
    __shared__ int cnt;
    if (threadIdx.x == 0) cnt = 0;
    __syncthreads();
    const float4* arow = (const float4*)(adj + (size_t)b * N);
    for (int c4 = threadIdx.x; c4 < N / 4; c4 += 256) {
      float4 v = arow[c4];
      int base = c4 * 4;
      if (v.x > 0.f) { int k = atomicAdd(&cnt, 1); if (k < CAP) cols[(size_t)b * CAP + k] = base; }
      if (v.y > 0.f) { int k = atomicAdd(&cnt, 1); if (k < CAP) cols[(size_t)b * CAP + k] = base + 1; }
      if (v.z > 0.f) { int k = atomicAdd(&cnt, 1); if (k < CAP) cols[(size_t)b * CAP + k] = base + 2; }
      if (v.w > 0.f) { int k = atomicAdd(&cnt, 1); if (k < CAP) cols[(size_t)b * CAP + k] = base + 3; }
    }
    __syncthreads();
    if (threadIdx.x == 0) counts[b] = cnt < CAP ? cnt : CAP;
  } else {
    int c = b - N;  // 0..575
    const float* W;
    unsigned short *hiP, *loP;
    if (c < 512) { W = W1; hiP = w1hi; loP = w1lo; }
    else         { W = W2; hiP = w2hi; loP = w2lo; c -= 512; }
    const float* Wp = W + (size_t)(c >> 6) * 512 * 64 + (c & 63);
    for (int k = threadIdx.x; k < 512; k += 256) {
      float v = Wp[(size_t)k * 64];
      unsigned short hb = f2bf(v);
      hiP[(size_t)c * 512 + k] = hb;
      loP[(size_t)c * 512 + k] = f2bf(v - bf2f(hb));
    }
  }
}

// ---------------- K2: split-precision bf16 MFMA GEMM + fused e/colsum ------
// C_head_major[by][4096][64] f32 = (Ahi+Alo) @ Beff (drop lo*lo, ~2^-17 rel).
// F32A=true: A staged from f32 source, hi/lo split in-register (layer 1).
// Epilogue: C tile routed through LDS (reuses As = exactly 128x64 f32);
// computes esrc/edst (shfl row-dot with aVec) and atomic column sums.
template <bool F32A>
__global__ __launch_bounds__(512) void mfma_gemm(const float* __restrict__ Af,
                                                 const unsigned short* __restrict__ Ahi,
                                                 const unsigned short* __restrict__ Alo,
                                                 const unsigned short* __restrict__ Bhi,
                                                 const unsigned short* __restrict__ Blo,
                                                 const float* __restrict__ aVec,
                                                 float* __restrict__ C,
                                                 float* __restrict__ esrc,
                                                 float* __restrict__ edst,
                                                 float* __restrict__ sumAtomic) {
  __shared__ unsigned short As[2][2][128 * 32];  // [buf][hi/lo][swz(m,k)]
  __shared__ unsigned short Bs[2][2][64 * 32];   // [buf][hi/lo][swz(c,k)]
  const int t = threadIdx.x;
  const int m0 = blockIdx.x * 128;
  const int c0 = blockIdx.y * 64;
  const int lane = t & 63, wave = t >> 6;
  const int g = lane >> 4, r = lane & 15;
  const int wm = (wave >> 1) * 32;
  const int wn = (wave & 1) * 32;
  const int sar = t >> 2, sak = (t & 3) * 8;
  const int tb = t & 255;
  const int sbr = tb >> 2, sbk = (tb & 3) * 8;
  const unsigned short* Bsel = (t < 256) ? Bhi : Blo;
  const int bhalf = (t < 256) ? 0 : 1;
  const int idxA = swz(sar, sak);
  const int idxB = swz(sbr, sbk);
  const size_t aOff = (size_t)(m0 + sar) * 512 + sak;
  const size_t bOff = (size_t)(c0 + sbr) * 512 + sbk;
  const f32x4 z = {0.f, 0.f, 0.f, 0.f};
  f32x4 acc[2][2];
  acc[0][0] = z; acc[0][1] = z; acc[1][0] = z; acc[1][1] = z;

  int4 a0, a1, b0;
  auto loadRegs = [&](int kb) {
    if constexpr (F32A) {
      float4 v0 = *(const float4*)(Af + aOff + kb);
      float4 v1 = *(const float4*)(Af + aOff + kb + 4);
      unsigned h0 = f2bf(v0.x), h1 = f2bf(v0.y), h2 = f2bf(v0.z), h3 = f2bf(v0.w);
      unsigned h4 = f2bf(v1.x), h5 = f2bf(v1.y), h6 = f2bf(v1.z), h7 = f2bf(v1.w);
      unsigned l0 = f2bf(v0.x - bf2f(h0)), l1 = f2bf(v0.y - bf2f(h1));
      unsigned l2 = f2bf(v0.z - bf2f(h2)), l3 = f2bf(v0.w - bf2f(h3));
      unsigned l4 = f2bf(v1.x - bf2f(h4)), l5 = f2bf(v1.y - bf2f(h5));
      unsigned l6 = f2bf(v1.z - bf2f(h6)), l7 = f2bf(v1.w - bf2f(h7));
      a0.x = h0 | (h1 << 16); a0.y = h2 | (h3 << 16);
      a0.z = h4 | (h5 << 16); a0.w = h6 | (h7 << 16);
      a1.x = l0 | (l1 << 16); a1.y = l2 | (l3 << 16);
      a1.z = l4 | (l5 << 16); a1.w = l6 | (l7 << 16);
    } else {
      a0 = *(const int4*)(Ahi + aOff + kb);
      a1 = *(const int4*)(Alo + aOff + kb);
    }
    b0 = *(const int4*)(Bsel + bOff + kb);
  };
  auto storeLds = [&](int buf) {
    *(int4*)(&As[buf][0][idxA]) = a0;
    *(int4*)(&As[buf][1][idxA]) = a1;
    *(int4*)(&Bs[buf][bhalf][idxB]) = b0;
  };

  loadRegs(0);
  storeLds(0);
  __syncthreads();

  for (int ch = 0; ch < 16; ++ch) {
    const int cur = ch & 1;
    if (ch < 15) loadRegs((ch + 1) * 32);  // issue early, hide under MFMA
    bf16x8 ah[2], al[2], bh[2], bl[2];
#pragma unroll
    for (int f = 0; f < 2; ++f) {
      int ia = swz(wm + f * 16 + r, 8 * g);
      int ib = swz(wn + f * 16 + r, 8 * g);
      ah[f] = *(const bf16x8*)(&As[cur][0][ia]);
      al[f] = *(const bf16x8*)(&As[cur][1][ia]);
      bh[f] = *(const bf16x8*)(&Bs[cur][0][ib]);
      bl[f] = *(const bf16x8*)(&Bs[cur][1][ib]);
    }
#pragma unroll
    for (int i = 0; i < 2; ++i)
#pragma unroll
      for (int j = 0; j < 2; ++j) {
        acc[i][j] = __builtin_amdgcn_mfma_f32_16x16x32_bf16(ah[i], bh[j], acc[i][j], 0, 0, 0);
        acc[i][j] = __builtin_amdgcn_mfma_f32_16x16x32_bf16(al[i], bh[j], acc[i][j], 0, 0, 0);
        acc[i][j] = __builtin_amdgcn_mfma_f32_16x16x32_bf16(ah[i], bl[j], acc[i][j], 0, 0, 0);
      }
    if (ch < 15) {
      storeLds(cur ^ 1);  // write-late into the other buffer
      __syncthreads();
    }
  }

  // ---- epilogue: C tile -> LDS -> global + esrc/edst + column sums ----
  __syncthreads();                 // all waves done reading As/Bs fragments
  float* Cs = (float*)&As[0][0][0];  // 32 KB = 128x64 f32 exactly
#pragma unroll
  for (int i = 0; i < 2; ++i)
#pragma unroll
    for (int j = 0; j < 2; ++j)
#pragma unroll
      for (int q = 0; q < 4; ++q)
        Cs[(wm + i * 16 + 4 * g + q) * 64 + wn + j * 16 + r] = acc[i][j][q];
  __syncthreads();
  float* Cp = C + ((size_t)blockIdx.y * N + m0) * 64;
  const float* aV = aVec + (size_t)blockIdx.y * 128;
  float as_ = aV[lane], ad_ = aV[64 + lane];
  float cs = 0.f;
#pragma unroll
  for (int rr = 0; rr < 16; ++rr) {
    int row = wave * 16 + rr;
    float v = Cs[row * 64 + lane];
    Cp[(size_t)row * 64 + lane] = v;
    cs += v;
    float s = v * as_, d = v * ad_;
#pragma unroll
    for (int off = 32; off; off >>= 1) {
      s += __shfl_xor(s, off);
      d += __shfl_xor(d, off);
    }
    if (lane == 0) {
      esrc[(size_t)blockIdx.y * N + m0 + row] = s;
      edst[(size_t)blockIdx.y * N + m0 + row] = d;
    }
  }
  atomicAdd(&sumAtomic[blockIdx.y * 64 + lane], cs);
}

// ---------------- K3: layer-1 attention, wave per (node,head) --------------
// head = blockIdx % 8 (XCD-local 1 MB head slab). float4 gathers: 16 lanes
// per neighbor row, 4 neighbors per instruction, shfl_xor(16/32) reduce.
__global__ __launch_bounds__(256) void gat_attn_l1(const float* __restrict__ Wh,
                                                   const float* __restrict__ esrc,
                                                   const float* __restrict__ edst,
                                                   const int* __restrict__ counts,
                                                   const int* __restrict__ cols,
                                                   const float* __restrict__ sumWh,
                                                   unsigned short* __restrict__ hhi,
                                                   unsigned short* __restrict__ hlo) {
  int h = blockIdx.x & 7;
  int wv = threadIdx.x >> 6;
  int lane = threadIdx.x & 63;
  int sg = lane >> 4, sl = lane & 15;
  int i = (blockIdx.x >> 3) * 4 + wv;
  int cnt = counts[i];
  __shared__ int jls[4][CAP];
  __shared__ float pls[4][CAP];
  const float* WhH = Wh + (size_t)h * N * 64;
  float4 acc = {0.f, 0.f, 0.f, 0.f};
  if (cnt == 0) {
    float4 sv = *(const float4*)(sumWh + h * 64 + 4 * sl);
    acc.x = sv.x * (1.0f / N); acc.y = sv.y * (1.0f / N);
    acc.z = sv.z * (1.0f / N); acc.w = sv.w * (1.0f / N);
  } else {
    const int* cl = cols + (size_t)i * CAP;
    jls[wv][lane] = (lane < cnt) ? cl[lane] : 0;
    jls[wv][lane + 64] = (lane + 64 < cnt) ? cl[lane + 64] : 0;
    float ei = esrc[h * N + i];
    const float* ed = edst + (size_t)h * N;
    float e0 = -1e30f, e1 = -1e30f;
    if (lane < cnt) {
      float e = ei + ed[jls[wv][lane]];
      e0 = (e > 0.f) ? e : LRELU_ALPHA * e;
    }
    if (lane + 64 < cnt) {
      float e = ei + ed[jls[wv][lane + 64]];
      e1 = (e > 0.f) ? e : LRELU_ALPHA * e;
    }
    float m = fmaxf(e0, e1);
#pragma unroll
    for (int off = 32; off; off >>= 1) m = fmaxf(m, __shfl_xor(m, off));
    float p0 = (lane < cnt) ? __expf(e0 - m) : 0.f;
    float p1 = (lane + 64 < cnt) ? __expf(e1 - m) : 0.f;
    float ssum = p0 + p1;
#pragma unroll
    for (int off = 32; off; off >>= 1) ssum += __shfl_xor(ssum, off);
    pls[wv][lane] = p0;       // zero-padded beyond cnt by construction
    pls[wv][lane + 64] = p1;  // own-wave write->read, no barrier needed
    int L = (cnt + 15) & ~15;  // <= CAP
    for (int k = 0; k < L; k += 16) {
      int j0 = jls[wv][k + sg];
      int j1 = jls[wv][k + 4 + sg];
      int j2 = jls[wv][k + 8 + sg];
      int j3 = jls[wv][k + 12 + sg];
      float4 v0 = *(const float4*)(WhH + ((size_t)j0 << 6) + 4 * sl);
      float4 v1 = *(const float4*)(WhH + ((size_t)j1 << 6) + 4 * sl);
      float4 v2 = *(const float4*)(WhH + ((size_t)j2 << 6) + 4 * sl);
      float4 v3 = *(const float4*)(WhH + ((size_t)j3 << 6) + 4 * sl);
      float q0 = pls[wv][k + sg];
      float q1 = pls[wv][k + 4 + sg];
      float q2 = pls[wv][k + 8 + sg];
      float q3 = pls[wv][k + 12 + sg];
      acc.x = fmaf(q0, v0.x, acc.x); acc.y = fmaf(q0, v0.y, acc.y);
      acc.z = fmaf(q0, v0.z, acc.z); acc.w = fmaf(q0, v0.w, acc.w);
      acc.x = fmaf(q1, v1.x, acc.x); acc.y = fmaf(q1, v1.y, acc.y);
      acc.z = fmaf(q1, v1.z, acc.z); acc.w = fmaf(q1, v1.w, acc.w);
      acc.x = fmaf(q2, v2.x, acc.x); acc.y = fmaf(q2, v2.y, acc.y);
      acc.z = fmaf(q2, v2.z, acc.z); acc.w = fmaf(q2, v2.w, acc.w);
      acc.x = fmaf(q3, v3.x, acc.x); acc.y = fmaf(q3, v3.y, acc.y);
      acc.z = fmaf(q3, v3.z, acc.z); acc.w = fmaf(q3, v3.w, acc.w);
    }
    // reduce across the 4 neighbor subgroups
    acc.x += __shfl_xor(acc.x, 16); acc.y += __shfl_xor(acc.y, 16);
    acc.z += __shfl_xor(acc.z, 16); acc.w += __shfl_xor(acc.w, 16);
    acc.x += __shfl_xor(acc.x, 32); acc.y += __shfl_xor(acc.y, 32);
    acc.z += __shfl_xor(acc.z, 32); acc.w += __shfl_xor(acc.w, 32);
    float inv = 1.0f / ssum;
    acc.x *= inv; acc.y *= inv; acc.z *= inv; acc.w *= inv;
  }
  // ELU + bf16 hi/lo store by lanes 0-15 (cols 4sl..4sl+3)
  if (sg == 0) {
    acc.x = (acc.x > 0.f) ? acc.x : expm1f(acc.x);
    acc.y = (acc.y > 0.f) ? acc.y : expm1f(acc.y);
    acc.z = (acc.z > 0.f) ? acc.z : expm1f(acc.z);
    acc.w = (acc.w > 0.f) ? acc.w : expm1f(acc.w);
    ushort4 hi4, lo4;
    hi4.x = f2bf(acc.x); lo4.x = f2bf(acc.x - bf2f(hi4.x));
    hi4.y = f2bf(acc.y); lo4.y = f2bf(acc.y - bf2f(hi4.y));
    hi4.z = f2bf(acc.z); lo4.z = f2bf(acc.z - bf2f(hi4.z));
    hi4.w = f2bf(acc.w); lo4.w = f2bf(acc.w - bf2f(hi4.w));
    size_t o = (size_t)i * 512 + h * 64 + 4 * sl;
    *(ushort4*)(hhi + o) = hi4;
    *(ushort4*)(hlo + o) = lo4;
  }
}

// ---------------- K4: layer-2 attention + fused g = hf @ W_score -----------
__global__ __launch_bounds__(256) void gat_attn_l2(const float* __restrict__ Wh,
                                                   const float* __restrict__ esrc,
                                                   const float* __restrict__ edst,
                                                   const int* __restrict__ counts,
                                                   const int* __restrict__ cols,
                                                   const float* __restrict__ sumWh,
                                                   const float* __restrict__ Wsc,
                                                   float* __restrict__ hf,
                                                   float* __restrict__ g) {
  __shared__ float Ws[64][64];
  int t = threadIdx.x;
#pragma unroll
  for (int j = 0; j < 4; ++j) {
    int q = t + j * 256;
    int k = q >> 4, cq = (q & 15) * 4;
    *(float4*)(&Ws[k][cq]) = *(const float4*)(Wsc + k * 64 + cq);
  }
  __syncthreads();
  int wv = t >> 6;
  int lane = t & 63;
  int sg = lane >> 4, sl = lane & 15;
  int i = (blockIdx.x << 2) + wv;
  int cnt = counts[i];
  __shared__ int jls[4][CAP];
  __shared__ float pls[4][CAP];
  float v;
  if (cnt == 0) {
    v = sumWh[lane] * (1.0f / N);
  } else {
    const int* cl = cols + (size_t)i * CAP;
    jls[wv][lane] = (lane < cnt) ? cl[lane] : 0;
    jls[wv][lane + 64] = (lane + 64 < cnt) ? cl[lane + 64] : 0;
    float ei = esrc[i];
    float e0 = -1e30f, e1 = -1e30f;
    if (lane < cnt) {
      float e = ei + edst[jls[wv][lane]];
      e0 = (e > 0.f) ? e : LRELU_ALPHA * e;
    }
    if (lane + 64 < cnt) {
      float e = ei + edst[jls[wv][lane + 64]];
      e1 = (e > 0.f) ? e : LRELU_ALPHA * e;
    }
    float m = fmaxf(e0, e1);
#pragma unroll
    for (int off = 32; off; off >>= 1) m = fmaxf(m, __shfl_xor(m, off));
    float p0 = (lane < cnt) ? __expf(e0 - m) : 0.f;
    float p1 = (lane + 64 < cnt) ? __expf(e1 - m) : 0.f;
    float ssum = p0 + p1;
#pragma unroll
    for (int off = 32; off; off >>= 1) ssum += __shfl_xor(ssum, off);
    pls[wv][lane] = p0;
    pls[wv][lane + 64] = p1;
    float4 acc = {0.f, 0.f, 0.f, 0.f};
    int L = (cnt + 15) & ~15;
    for (int k = 0; k < L; k += 16) {
      int j0 = jls[wv][k + sg];
      int j1 = jls[wv][k + 4 + sg];
      int j2 = jls[wv][k + 8 + sg];
      int j3 = jls[wv][k + 12 + sg];
      float4 v0 = *(const float4*)(Wh + ((size_t)j0 << 6) + 4 * sl);
      float4 v1 = *(const float4*)(Wh + ((size_t)j1 << 6) + 4 * sl);
      float4 v2 = *(const float4*)(Wh + ((size_t)j2 << 6) + 4 * sl);
      float4 v3 = *(const float4*)(Wh + ((size_t)j3 << 6) + 4 * sl);
      float q0 = pls[wv][k + sg];
      float q1 = pls[wv][k + 4 + sg];
      float q2 = pls[wv][k + 8 + sg];
      float q3 = pls[wv][k + 12 + sg];
      acc.x = fmaf(q0, v0.x, acc.x); acc.y = fmaf(q0, v0.y, acc.y);
      acc.z = fmaf(q0, v0.z, acc.z); acc.w = fmaf(q0, v0.w, acc.w);
      acc.x = fmaf(q1, v1.x, acc.x); acc.y = fmaf(q1, v1.y, acc.y);
      acc.z = fmaf(q1, v1.z, acc.z); acc.w = fmaf(q1, v1.w, acc.w);
      acc.x = fmaf(q2, v2.x, acc.x); acc.y = fmaf(q2, v2.y, acc.y);
      acc.z = fmaf(q2, v2.z, acc.z); acc.w = fmaf(q2, v2.w, acc.w);
      acc.x = fmaf(q3, v3.x, acc.x); acc.y = fmaf(q3, v3.y, acc.y);
      acc.z = fmaf(q3, v3.z, acc.z); acc.w = fmaf(q3, v3.w, acc.w);
    }
    acc.x += __shfl_xor(acc.x, 16); acc.y += __shfl_xor(acc.y, 16);
    acc.z += __shfl_xor(acc.z, 16); acc.w += __shfl_xor(acc.w, 16);
    acc.x += __shfl_xor(acc.x, 32); acc.y += __shfl_xor(acc.y, 32);
    acc.z += __shfl_xor(acc.z, 32); acc.w += __shfl_xor(acc.w, 32);
    // redistribute: col=lane lives in component lane&3 of source lane lane>>2
    float cx = __shfl(acc.x, lane >> 2);
    float cy = __shfl(acc.y, lane >> 2);
    float cz = __shfl(acc.z, lane >> 2);
    float cw = __shfl(acc.w, lane >> 2);
    int cmp = lane & 3;
    v = (cmp == 0) ? cx : (cmp == 1) ? cy : (cmp == 2) ? cz : cw;
    v /= ssum;
  }
  v = (v > 0.f) ? v : expm1f(v);  // ELU
  hf[((size_t)i << 6) + lane] = v;
  float gacc = 0.f;
#pragma unroll
  for (int k = 0; k < 64; ++k)
    gacc = fmaf(__shfl(v, k), Ws[k][lane], gacc);
  g[((size_t)i << 6) + lane] = gacc;
}

// ---------------- K5: pairwise bilinear scores (4 pairs/wave, float4) ------
__global__ __launch_bounds__(256) void score_quad(const float* __restrict__ g,
                                                  const float* __restrict__ hf,
                                                  const int* __restrict__ p1,
                                                  const int* __restrict__ p2,
                                                  float* __restrict__ out) {
  int w = threadIdx.x >> 6;
  int lane = threadIdx.x & 63;
  int sub = lane >> 4, sl = lane & 15;
  int p = (((blockIdx.x << 2) + w) << 2) + sub;
  int i1 = p1[p], i2 = p2[p];
  float4 ga = *(const float4*)(g + ((size_t)i1 << 6) + sl * 4);
  float4 hb = *(const float4*)(hf + ((size_t)i2 << 6) + sl * 4);
  float v = ga.x * hb.x + ga.y * hb.y + ga.z * hb.z + ga.w * hb.w;
#pragma unroll
  for (int off = 8; off; off >>= 1) v += __shfl_xor(v, off);
  if (sl == 0) out[p] = v;
}

extern "C" void kernel_launch(void* const* d_in, const int* in_sizes, int n_in,
                              void* d_out, int out_size, void* d_ws, size_t ws_size,
                              hipStream_t stream) {
  const float* x       = (const float*)d_in[0];
  const float* adj     = (const float*)d_in[1];
  const float* W_heads = (const float*)d_in[2];
  const float* a_heads = (const float*)d_in[3];
  const float* W_out   = (const float*)d_in[4];
  const float* a_out   = (const float*)d_in[5];
  const float* W_score = (const float*)d_in[6];
  const int* p1        = (const int*)d_in[7];
  const int* p2        = (const int*)d_in[8];
  float* out           = (float*)d_out;

  char* ws = (char*)d_ws;
  size_t off = 0;
  auto alloc = [&](size_t bytes) -> void* {
    void* p = ws + off;
    off += (bytes + 255) & ~(size_t)255;
    return p;
  };
  int*   counts = (int*)alloc((size_t)N * 4);
  int*   cols   = (int*)alloc((size_t)N * CAP * 4);
  unsigned short* wt1hi = (unsigned short*)alloc((size_t)512 * 512 * 2);
  unsigned short* wt1lo = (unsigned short*)alloc((size_t)512 * 512 * 2);
  unsigned short* wt2hi = (unsigned short*)alloc((size_t)64 * 512 * 2);
  unsigned short* wt2lo = (unsigned short*)alloc((size_t)64 * 512 * 2);
  float* Wh1    = (float*)alloc((size_t)NHEADS * N * 64 * 4);  // head-major
  float* es1    = (float*)alloc((size_t)NHEADS * N * 4);
  float* ed1    = (float*)alloc((size_t)NHEADS * N * 4);
  float* sum1   = (float*)alloc((size_t)512 * 4);
  unsigned short* h1hi = (unsigned short*)alloc((size_t)N * 512 * 2);
  unsigned short* h1lo = (unsigned short*)alloc((size_t)N * 512 * 2);
  float* Wh2    = (float*)alloc((size_t)N * 64 * 4);
  float* es2    = (float*)alloc((size_t)N * 4);
  float* ed2    = (float*)alloc((size_t)N * 4);
  float* sum2   = (float*)alloc((size_t)64 * 4);
  float* hf     = (float*)alloc((size_t)N * 64 * 4);
  float* g      = (float*)alloc((size_t)N * 64 * 4);

  // K1: CSR + weight prep + sum zeroing (one kernel)
  prep_all<<<N + 576, 256, 0, stream>>>(adj, W_heads, W_out, counts, cols,
                                        wt1hi, wt1lo, wt2hi, wt2lo, sum1, sum2);

  // K2: layer-1 GEMM (f32 A converted in-kernel) + fused e/colsum
  mfma_gemm<true><<<dim3(N / 128, NHEADS), 512, 0, stream>>>(
      x, nullptr, nullptr, wt1hi, wt1lo, a_heads, Wh1, es1, ed1, sum1);

  // K3: layer-1 attention -> h1 bf16 hi/lo
  gat_attn_l1<<<(N / 4) * NHEADS, 256, 0, stream>>>(Wh1, es1, ed1, counts, cols,
                                                    sum1, h1hi, h1lo);

  // K4: layer-2 GEMM + fused e/colsum
  mfma_gemm<false><<<dim3(N / 128, 1), 512, 0, stream>>>(
      nullptr, h1hi, h1lo, wt2hi, wt2lo, a_out, Wh2, es2, ed2, sum2);

  // K5: layer-2 attention + fused score GEMM
  gat_attn_l2<<<N / 4, 256, 0, stream>>>(Wh2, es2, ed2, counts, cols, sum2,
                                         W_score, hf, g);

  // K6: pairwise scores
  score_quad<<<P_PAIRS / 16, 256, 0, stream>>>(g, hf, p1, p2, out);
}